// Round 1
// baseline (1668.017 us; speedup 1.0000x reference)
//
#include <hip/hip_runtime.h>

#define DIM 2048
#define HDIM 128
#define NH 16
#define SEQ 2048
#define BATCH 2
#define MROWS (BATCH*SEQ)   // 4096

typedef __attribute__((ext_vector_type(8))) short short8;
typedef __attribute__((ext_vector_type(4))) float f32x4;

__device__ __forceinline__ unsigned short f2bf(float f) {
  union { float f; unsigned u; } v; v.f = f;
  unsigned r = v.u + 0x7FFFu + ((v.u >> 16) & 1u);
  return (unsigned short)(r >> 16);
}
__device__ __forceinline__ float bf2f(unsigned short b) {
  union { unsigned u; float f; } v; v.u = ((unsigned)b) << 16;
  return v.f;
}

__device__ __forceinline__ void gload16(const void* g, void* l) {
  __builtin_amdgcn_global_load_lds((const __attribute__((address_space(1))) unsigned int*)g,
                                   (__attribute__((address_space(3))) unsigned int*)l,
                                   16, 0, 0);
}

// ---------------- RMSNorm: fp32 [rows][2048] -> bf16 ----------------
__global__ __launch_bounds__(256) void rmsnorm_kernel(const float* __restrict__ x,
                                                      const float* __restrict__ w,
                                                      unsigned short* __restrict__ out) {
  const int row = blockIdx.x;
  const int t = threadIdx.x;
  const float* xr = x + (size_t)row * DIM;
  float4 v0 = ((const float4*)xr)[t*2];
  float4 v1 = ((const float4*)xr)[t*2+1];
  float ss = v0.x*v0.x + v0.y*v0.y + v0.z*v0.z + v0.w*v0.w
           + v1.x*v1.x + v1.y*v1.y + v1.z*v1.z + v1.w*v1.w;
  #pragma unroll
  for (int i = 1; i < 64; i <<= 1) ss += __shfl_xor(ss, i);
  __shared__ float red[4];
  if ((t & 63) == 0) red[t >> 6] = ss;
  __syncthreads();
  float sum = red[0] + red[1] + red[2] + red[3];
  float sc = rsqrtf(sum * (1.0f/DIM) + 1e-6f);
  const float* wr = w + t*8;
  unsigned short ob[8];
  ob[0] = f2bf(v0.x*sc*wr[0]); ob[1] = f2bf(v0.y*sc*wr[1]);
  ob[2] = f2bf(v0.z*sc*wr[2]); ob[3] = f2bf(v0.w*sc*wr[3]);
  ob[4] = f2bf(v1.x*sc*wr[4]); ob[5] = f2bf(v1.y*sc*wr[5]);
  ob[6] = f2bf(v1.z*sc*wr[6]); ob[7] = f2bf(v1.w*sc*wr[7]);
  uint4 pk;
  pk.x = (unsigned)ob[0] | ((unsigned)ob[1] << 16);
  pk.y = (unsigned)ob[2] | ((unsigned)ob[3] << 16);
  pk.z = (unsigned)ob[4] | ((unsigned)ob[5] << 16);
  pk.w = (unsigned)ob[6] | ((unsigned)ob[7] << 16);
  *((uint4*)(out + (size_t)row*DIM + t*8)) = pk;
}

// ------------- Weight transpose: fp32 [K][N] -> bf16 [N][K] -------------
__global__ __launch_bounds__(256) void transpose_w_kernel(const float* __restrict__ W,
                                                          unsigned short* __restrict__ Wt,
                                                          int K, int N) {
  __shared__ float tile[32][33];
  const int k0 = blockIdx.x*32, n0 = blockIdx.y*32;
  const int tx = threadIdx.x, ty = threadIdx.y;
  #pragma unroll
  for (int i=0;i<4;i++) tile[ty+i*8][tx] = W[(size_t)(k0+ty+i*8)*N + n0+tx];
  __syncthreads();
  #pragma unroll
  for (int i=0;i<4;i++) Wt[(size_t)(n0+ty+i*8)*K + k0+tx] = f2bf(tile[tx][ty+i*8]);
}

// ------------- V transpose (bf16): [b*S][2048] -> [b*2048][S] -------------
__global__ __launch_bounds__(256) void transpose_v_kernel(const unsigned short* __restrict__ v,
                                                          unsigned short* __restrict__ vt) {
  __shared__ unsigned short tile[32][33];
  const int b = blockIdx.z;
  const int s0 = blockIdx.x*32, c0 = blockIdx.y*32;
  const int tx = threadIdx.x, ty = threadIdx.y;
  #pragma unroll
  for (int i=0;i<4;i++) tile[ty+i*8][tx] = v[((size_t)(b*SEQ + s0+ty+i*8))*DIM + c0+tx];
  __syncthreads();
  #pragma unroll
  for (int i=0;i<4;i++) vt[((size_t)(b*DIM + c0+ty+i*8))*SEQ + s0+tx] = tile[tx][ty+i*8];
}

// ------------- RoPE in-place on bf16 [4096][2048] -------------
__global__ __launch_bounds__(256) void rope_kernel(unsigned short* __restrict__ qk,
                                                   const float* __restrict__ cosb,
                                                   const float* __restrict__ sinb) {
  const size_t idx = (size_t)blockIdx.x * 256 + threadIdx.x; // pair index
  const int d = (int)(idx & 63);
  const int h = (int)((idx >> 6) & 15);
  const int row = (int)(idx >> 10);       // 0..4095
  const int s = row & (SEQ-1);
  const size_t base = (size_t)row * DIM + h*HDIM + d;
  float a  = bf2f(qk[base]);
  float bq = bf2f(qk[base+64]);
  float c1 = cosb[s*HDIM + d],    s1 = sinb[s*HDIM + d];
  float c2 = cosb[s*HDIM + d+64], s2 = sinb[s*HDIM + d+64];
  qk[base]    = f2bf(a*c1 - bq*s1);
  qk[base+64] = f2bf(bq*c2 + a*s2);
}

// ------------- GEMM: C[M][N] = A[M][K](bf16) @ Bt[N][K]^T (bf16) -------------
// EPI 0: bf16 out.  EPI 1: fp32 out = acc + aux.  EPI 2: dual-B swiglu -> bf16.
template<int EPI>
__global__ __launch_bounds__(256) void gemm_kernel(const unsigned short* __restrict__ A,
                                                   const unsigned short* __restrict__ Bt,
                                                   const unsigned short* __restrict__ Bt2,
                                                   const float* __restrict__ aux,
                                                   void* __restrict__ outp,
                                                   int M, int N, int K) {
  const int t = threadIdx.x;
  const int lane = t & 63, w = t >> 6;
  const int m0 = blockIdx.y * 128, n0 = blockIdx.x * 128;
  const int wr = w >> 1, wc = w & 1;
  __shared__ unsigned short As[128*32];
  __shared__ unsigned short Bs[128*32];
  __shared__ unsigned short Bs2[(EPI==2) ? 128*32 : 8];
  f32x4 acc[4][4] = {};
  f32x4 acc2[4][4] = {};
  const int srow = lane >> 2;        // staging row within 16-row chunk
  const int scol = (lane & 3) * 8;   // staging k offset
  const int lr = lane & 15, lg = lane >> 4;

  for (int k0 = 0; k0 < K; k0 += 32) {
    #pragma unroll
    for (int i = 0; i < 2; i++) {
      const int chunk = w*2 + i;
      const int row = chunk*16 + srow;
      gload16(&A [(size_t)(m0+row)*K + k0 + scol], &As [chunk*512]);
      gload16(&Bt[(size_t)(n0+row)*K + k0 + scol], &Bs [chunk*512]);
      if constexpr (EPI==2)
        gload16(&Bt2[(size_t)(n0+row)*K + k0 + scol], &Bs2[chunk*512]);
    }
    __syncthreads();   // drains vmcnt -> tiles ready
    short8 af[4], bfr[4], bfr2[4];
    #pragma unroll
    for (int m=0;m<4;m++) af[m]  = *(const short8*)&As [(wr*64 + m*16 + lr)*32 + lg*8];
    #pragma unroll
    for (int n=0;n<4;n++) bfr[n] = *(const short8*)&Bs [(wc*64 + n*16 + lr)*32 + lg*8];
    if constexpr (EPI==2) {
      #pragma unroll
      for (int n=0;n<4;n++) bfr2[n] = *(const short8*)&Bs2[(wc*64 + n*16 + lr)*32 + lg*8];
    }
    #pragma unroll
    for (int m=0;m<4;m++)
      #pragma unroll
      for (int n=0;n<4;n++) {
        acc[m][n] = __builtin_amdgcn_mfma_f32_16x16x32_bf16(af[m], bfr[n], acc[m][n], 0,0,0);
        if constexpr (EPI==2)
          acc2[m][n] = __builtin_amdgcn_mfma_f32_16x16x32_bf16(af[m], bfr2[n], acc2[m][n], 0,0,0);
      }
    __syncthreads();   // all waves done reading before next stage
  }

  #pragma unroll
  for (int m=0;m<4;m++)
    #pragma unroll
    for (int n=0;n<4;n++)
      #pragma unroll
      for (int r=0;r<4;r++) {
        const int row = m0 + wr*64 + m*16 + lg*4 + r;
        const int col = n0 + wc*64 + n*16 + lr;
        const size_t idx = (size_t)row*N + col;
        if constexpr (EPI==0) {
          ((unsigned short*)outp)[idx] = f2bf(acc[m][n][r]);
        } else if constexpr (EPI==1) {
          ((float*)outp)[idx] = acc[m][n][r] + aux[idx];
        } else {
          float u = acc[m][n][r], g = acc2[m][n][r];
          float sg = u / (1.0f + __expf(-u));
          ((unsigned short*)outp)[idx] = f2bf(sg * g);
        }
      }
}

// ------------- Flash attention (causal). q,k: bf16 [4096][2048]; vt: bf16 [b*2048][S] -------------
__global__ __launch_bounds__(256) void attn_kernel(const unsigned short* __restrict__ q,
                                                   const unsigned short* __restrict__ k,
                                                   const unsigned short* __restrict__ vt,
                                                   unsigned short* __restrict__ ao) {
  const int t = threadIdx.x, lane = t & 63, w = t >> 6;
  const int qt = blockIdx.x, bh = blockIdx.y;
  const int b = bh >> 4, h = bh & 15;
  const int lr = lane & 15, lg = lane >> 4;
  const int q0 = qt*64 + w*16;           // this wave's q-row start
  __shared__ unsigned short P[4][16*40]; // per-wave P tile, stride 40 (16B-aligned rows)
  unsigned short* pw = &P[w][0];

  short8 aq[4];
  {
    const unsigned short* qp = q + ((size_t)(b*SEQ + q0 + lr))*DIM + h*HDIM;
    #pragma unroll
    for (int c=0;c<4;c++) aq[c] = *(const short8*)(qp + c*32 + lg*8);
  }
  f32x4 accO[8] = {};
  float mrow[4], lrow[4];
  int rq[4];
  #pragma unroll
  for (int r=0;r<4;r++) { mrow[r] = -3.0e38f; lrow[r] = 0.0f; rq[r] = q0 + lg*4 + r; }
  const float scale = 0.08838834764831845f; // 1/sqrt(128)
  const size_t kbase = (size_t)(b*SEQ)*DIM + h*HDIM;
  const size_t vbase = (size_t)(bh*HDIM)*SEQ;
  const int kv_end = q0 + 16;             // causal: kv <= q0+15

  for (int kv0 = 0; kv0 < kv_end; kv0 += 32) {
    f32x4 sc[2] = {};
    #pragma unroll
    for (int blk=0;blk<2;blk++) {
      const unsigned short* kp = k + kbase + (size_t)(kv0 + blk*16 + lr)*DIM;
      #pragma unroll
      for (int c=0;c<4;c++) {
        short8 bk = *(const short8*)(kp + c*32 + lg*8);
        sc[blk] = __builtin_amdgcn_mfma_f32_16x16x32_bf16(aq[c], bk, sc[blk], 0,0,0);
      }
    }
    float fac[4];
    #pragma unroll
    for (int r=0;r<4;r++) {
      #pragma unroll
      for (int blk=0;blk<2;blk++) {
        float s = sc[blk][r] * scale;
        if (kv0 + blk*16 + lr > rq[r]) s = -1.0e30f;
        sc[blk][r] = s;
      }
      float pm = fmaxf(sc[0][r], sc[1][r]);
      #pragma unroll
      for (int x=1;x<16;x<<=1) pm = fmaxf(pm, __shfl_xor(pm, x));
      float mn = fmaxf(mrow[r], pm);
      fac[r] = __expf(mrow[r] - mn);
      float p0 = __expf(sc[0][r] - mn), p1 = __expf(sc[1][r] - mn);
      sc[0][r] = p0; sc[1][r] = p1;
      float ps = p0 + p1;
      #pragma unroll
      for (int x=1;x<16;x<<=1) ps += __shfl_xor(ps, x);
      lrow[r] = lrow[r]*fac[r] + ps;
      mrow[r] = mn;
    }
    #pragma unroll
    for (int n=0;n<8;n++)
      #pragma unroll
      for (int r=0;r<4;r++) accO[n][r] *= fac[r];
    // P -> LDS (bf16)
    #pragma unroll
    for (int blk=0;blk<2;blk++)
      #pragma unroll
      for (int r=0;r<4;r++)
        pw[(lg*4+r)*40 + blk*16 + lr] = f2bf(sc[blk][r]);
    short8 ap = *(const short8*)&pw[lr*40 + lg*8];
    #pragma unroll
    for (int n=0;n<8;n++) {
      short8 bv = *(const short8*)(vt + vbase + (size_t)(n*16 + lr)*SEQ + kv0 + lg*8);
      accO[n] = __builtin_amdgcn_mfma_f32_16x16x32_bf16(ap, bv, accO[n], 0,0,0);
    }
  }
  #pragma unroll
  for (int n=0;n<8;n++)
    #pragma unroll
    for (int r=0;r<4;r++)
      ao[((size_t)(b*SEQ + rq[r]))*DIM + h*HDIM + n*16 + lr] = f2bf(accO[n][r] / lrow[r]);
}

// ----------------------------------------------------------------------------
extern "C" void kernel_launch(void* const* d_in, const int* in_sizes, int n_in,
                              void* d_out, int out_size, void* d_ws, size_t ws_size,
                              hipStream_t stream) {
  (void)in_sizes; (void)n_in; (void)out_size; (void)ws_size;
  const float* x    = (const float*)d_in[0];
  const float* cosb = (const float*)d_in[1];
  const float* sinb = (const float*)d_in[2];
  // d_in[3] = mask (causal, implemented analytically)
  const float* anw  = (const float*)d_in[4];
  const float* fnw  = (const float*)d_in[5];
  const float* wq   = (const float*)d_in[6];
  const float* wk   = (const float*)d_in[7];
  const float* wv   = (const float*)d_in[8];
  const float* wo   = (const float*)d_in[9];
  const float* w1   = (const float*)d_in[10];
  const float* w2   = (const float*)d_in[11];
  const float* w3   = (const float*)d_in[12];

  char* ws = (char*)d_ws;
  const size_t SZ = 16777216; // 16 MiB unit (4096*2048 bf16)
  unsigned short* h   = (unsigned short*)(ws);
  unsigned short* qb  = (unsigned short*)(ws + 1*SZ);
  unsigned short* kb  = (unsigned short*)(ws + 2*SZ);
  unsigned short* vb  = (unsigned short*)(ws + 3*SZ);
  unsigned short* aob = (unsigned short*)(ws + 4*SZ);
  unsigned short* mid = qb;                 // [4096][8192] bf16, reuses q..ao (67 MiB)
  float* x1 = (float*)(ws + 5*SZ);          // 32 MiB fp32
  char* wt  = ws + 5*SZ + 2*SZ;             // 64 MiB weight/Vt scratch
  unsigned short* wqT = (unsigned short*)wt;
  unsigned short* wkT = (unsigned short*)(wt + 8388608);
  unsigned short* wvT = (unsigned short*)(wt + 2*8388608);
  unsigned short* vtb = (unsigned short*)wt;            // after QKV gemms
  unsigned short* woT = (unsigned short*)wt;            // after attention
  unsigned short* w1T = (unsigned short*)wt;            // 32 MiB
  unsigned short* w3T = (unsigned short*)(wt + 33554432);
  unsigned short* w2T = (unsigned short*)wt;

  dim3 b256(256);
  dim3 tb(32, 8);

  rmsnorm_kernel<<<dim3(MROWS), b256, 0, stream>>>(x, anw, h);

  transpose_w_kernel<<<dim3(64,64), tb, 0, stream>>>(wq, wqT, 2048, 2048);
  transpose_w_kernel<<<dim3(64,64), tb, 0, stream>>>(wk, wkT, 2048, 2048);
  transpose_w_kernel<<<dim3(64,64), tb, 0, stream>>>(wv, wvT, 2048, 2048);

  gemm_kernel<0><<<dim3(16,32), b256, 0, stream>>>(h, wqT, nullptr, nullptr, qb, MROWS, 2048, 2048);
  gemm_kernel<0><<<dim3(16,32), b256, 0, stream>>>(h, wkT, nullptr, nullptr, kb, MROWS, 2048, 2048);
  gemm_kernel<0><<<dim3(16,32), b256, 0, stream>>>(h, wvT, nullptr, nullptr, vb, MROWS, 2048, 2048);

  rope_kernel<<<dim3(16384), b256, 0, stream>>>(qb, cosb, sinb);
  rope_kernel<<<dim3(16384), b256, 0, stream>>>(kb, cosb, sinb);

  transpose_v_kernel<<<dim3(64,64,2), tb, 0, stream>>>(vb, vtb);

  attn_kernel<<<dim3(32,32), b256, 0, stream>>>(qb, kb, vtb, aob);

  transpose_w_kernel<<<dim3(64,64), tb, 0, stream>>>(wo, woT, 2048, 2048);
  gemm_kernel<1><<<dim3(16,32), b256, 0, stream>>>(aob, woT, nullptr, x, x1, MROWS, 2048, 2048);

  rmsnorm_kernel<<<dim3(MROWS), b256, 0, stream>>>(x1, fnw, h);

  transpose_w_kernel<<<dim3(64,256), tb, 0, stream>>>(w1, w1T, 2048, 8192);
  transpose_w_kernel<<<dim3(64,256), tb, 0, stream>>>(w3, w3T, 2048, 8192);
  gemm_kernel<2><<<dim3(64,32), b256, 0, stream>>>(h, w1T, w3T, nullptr, mid, MROWS, 8192, 2048);

  transpose_w_kernel<<<dim3(256,64), tb, 0, stream>>>(w2, w2T, 8192, 2048);
  gemm_kernel<1><<<dim3(16,32), b256, 0, stream>>>(mid, w2T, nullptr, x1, (float*)d_out, MROWS, 2048, 8192);
}

// Round 2
// 1516.210 us; speedup vs baseline: 1.1001x; 1.1001x over previous
//
#include <hip/hip_runtime.h>

#define DIM 2048
#define HDIM 128
#define NH 16
#define SEQ 2048
#define BATCH 2
#define MROWS (BATCH*SEQ)   // 4096

typedef __attribute__((ext_vector_type(8))) short short8;
typedef __attribute__((ext_vector_type(4))) float f32x4;

__device__ __forceinline__ unsigned short f2bf(float f) {
  union { float f; unsigned u; } v; v.f = f;
  unsigned r = v.u + 0x7FFFu + ((v.u >> 16) & 1u);
  return (unsigned short)(r >> 16);
}
__device__ __forceinline__ float bf2f(unsigned short b) {
  union { unsigned u; float f; } v; v.u = ((unsigned)b) << 16;
  return v.f;
}

__device__ __forceinline__ void gload16(const void* g, void* l) {
  __builtin_amdgcn_global_load_lds((const __attribute__((address_space(1))) unsigned int*)g,
                                   (__attribute__((address_space(3))) unsigned int*)l,
                                   16, 0, 0);
}

// ---------------- RMSNorm: fp32 [rows][2048] -> bf16 ----------------
__global__ __launch_bounds__(256) void rmsnorm_kernel(const float* __restrict__ x,
                                                      const float* __restrict__ w,
                                                      unsigned short* __restrict__ out) {
  const int row = blockIdx.x;
  const int t = threadIdx.x;
  const float* xr = x + (size_t)row * DIM;
  float4 v0 = ((const float4*)xr)[t*2];
  float4 v1 = ((const float4*)xr)[t*2+1];
  float ss = v0.x*v0.x + v0.y*v0.y + v0.z*v0.z + v0.w*v0.w
           + v1.x*v1.x + v1.y*v1.y + v1.z*v1.z + v1.w*v1.w;
  #pragma unroll
  for (int i = 1; i < 64; i <<= 1) ss += __shfl_xor(ss, i);
  __shared__ float red[4];
  if ((t & 63) == 0) red[t >> 6] = ss;
  __syncthreads();
  float sum = red[0] + red[1] + red[2] + red[3];
  float sc = rsqrtf(sum * (1.0f/DIM) + 1e-6f);
  const float* wr = w + t*8;
  unsigned short ob[8];
  ob[0] = f2bf(v0.x*sc*wr[0]); ob[1] = f2bf(v0.y*sc*wr[1]);
  ob[2] = f2bf(v0.z*sc*wr[2]); ob[3] = f2bf(v0.w*sc*wr[3]);
  ob[4] = f2bf(v1.x*sc*wr[4]); ob[5] = f2bf(v1.y*sc*wr[5]);
  ob[6] = f2bf(v1.z*sc*wr[6]); ob[7] = f2bf(v1.w*sc*wr[7]);
  uint4 pk;
  pk.x = (unsigned)ob[0] | ((unsigned)ob[1] << 16);
  pk.y = (unsigned)ob[2] | ((unsigned)ob[3] << 16);
  pk.z = (unsigned)ob[4] | ((unsigned)ob[5] << 16);
  pk.w = (unsigned)ob[6] | ((unsigned)ob[7] << 16);
  *((uint4*)(out + (size_t)row*DIM + t*8)) = pk;
}

// ------------- Weight transpose: fp32 [K][N] -> bf16 [N][K] -------------
__global__ __launch_bounds__(256) void transpose_w_kernel(const float* __restrict__ W,
                                                          unsigned short* __restrict__ Wt,
                                                          int K, int N) {
  __shared__ float tile[32][33];
  const int k0 = blockIdx.x*32, n0 = blockIdx.y*32;
  const int tx = threadIdx.x, ty = threadIdx.y;
  #pragma unroll
  for (int i=0;i<4;i++) tile[ty+i*8][tx] = W[(size_t)(k0+ty+i*8)*N + n0+tx];
  __syncthreads();
  #pragma unroll
  for (int i=0;i<4;i++) Wt[(size_t)(n0+ty+i*8)*K + k0+tx] = f2bf(tile[tx][ty+i*8]);
}

// ------------- V transpose (bf16): [b*S][2048] -> [b*2048][S] -------------
__global__ __launch_bounds__(256) void transpose_v_kernel(const unsigned short* __restrict__ v,
                                                          unsigned short* __restrict__ vt) {
  __shared__ unsigned short tile[32][33];
  const int b = blockIdx.z;
  const int s0 = blockIdx.x*32, c0 = blockIdx.y*32;
  const int tx = threadIdx.x, ty = threadIdx.y;
  #pragma unroll
  for (int i=0;i<4;i++) tile[ty+i*8][tx] = v[((size_t)(b*SEQ + s0+ty+i*8))*DIM + c0+tx];
  __syncthreads();
  #pragma unroll
  for (int i=0;i<4;i++) vt[((size_t)(b*DIM + c0+ty+i*8))*SEQ + s0+tx] = tile[tx][ty+i*8];
}

// ------------- RoPE in-place on bf16 [4096][2048] -------------
__global__ __launch_bounds__(256) void rope_kernel(unsigned short* __restrict__ qk,
                                                   const float* __restrict__ cosb,
                                                   const float* __restrict__ sinb) {
  const size_t idx = (size_t)blockIdx.x * 256 + threadIdx.x; // pair index
  const int d = (int)(idx & 63);
  const int h = (int)((idx >> 6) & 15);
  const int row = (int)(idx >> 10);       // 0..4095
  const int s = row & (SEQ-1);
  const size_t base = (size_t)row * DIM + h*HDIM + d;
  float a  = bf2f(qk[base]);
  float bq = bf2f(qk[base+64]);
  float c1 = cosb[s*HDIM + d],    s1 = sinb[s*HDIM + d];
  float c2 = cosb[s*HDIM + d+64], s2 = sinb[s*HDIM + d+64];
  qk[base]    = f2bf(a*c1 - bq*s1);
  qk[base+64] = f2bf(bq*c2 + a*s2);
}

// ------------- GEMM: C[M][N] = A[M][K](bf16) @ Bt[N][K]^T (bf16) -------------
// EPI 0: bf16 out.  EPI 1: fp32 out = acc + aux.
// EPI 3: out(bf16, in-place u) = silu(u) * acc.
template<int EPI>
__global__ __launch_bounds__(256) void gemm_kernel(const unsigned short* __restrict__ A,
                                                   const unsigned short* __restrict__ Bt,
                                                   const float* __restrict__ aux,
                                                   void* outp,
                                                   int M, int N, int K) {
  const int t = threadIdx.x;
  const int lane = t & 63, w = t >> 6;
  // bijective XCD-chunked swizzle (nwg % 8 == 0 for all our grids; gridDim.x pow2)
  const int bid0 = blockIdx.y * gridDim.x + blockIdx.x;
  const int nwg = gridDim.x * gridDim.y;
  const int s = ((bid0 & 7) * (nwg >> 3)) + (bid0 >> 3);
  const int gxsh = 31 - __clz(gridDim.x);
  const int bx = s & (gridDim.x - 1);
  const int by = s >> gxsh;
  const int m0 = by * 128, n0 = bx * 128;
  const int wr = w >> 1, wc = w & 1;
  __shared__ unsigned short As[128*32];
  __shared__ unsigned short Bs[128*32];
  f32x4 acc[4][4] = {};
  const int srow = lane >> 2;        // staging row within 16-row chunk
  const int scol = (lane & 3) * 8;   // staging k offset
  const int lr = lane & 15, lg = lane >> 4;

  for (int k0 = 0; k0 < K; k0 += 32) {
    #pragma unroll
    for (int i = 0; i < 2; i++) {
      const int chunk = w*2 + i;
      const int row = chunk*16 + srow;
      gload16(&A [(size_t)(m0+row)*K + k0 + scol], &As [chunk*512]);
      gload16(&Bt[(size_t)(n0+row)*K + k0 + scol], &Bs [chunk*512]);
    }
    __syncthreads();   // drains vmcnt -> tiles ready
    short8 af[4], bfr[4];
    #pragma unroll
    for (int m=0;m<4;m++) af[m]  = *(const short8*)&As [(wr*64 + m*16 + lr)*32 + lg*8];
    #pragma unroll
    for (int n=0;n<4;n++) bfr[n] = *(const short8*)&Bs [(wc*64 + n*16 + lr)*32 + lg*8];
    #pragma unroll
    for (int m=0;m<4;m++)
      #pragma unroll
      for (int n=0;n<4;n++)
        acc[m][n] = __builtin_amdgcn_mfma_f32_16x16x32_bf16(af[m], bfr[n], acc[m][n], 0,0,0);
    __syncthreads();   // all waves done reading before next stage
  }

  #pragma unroll
  for (int m=0;m<4;m++)
    #pragma unroll
    for (int n=0;n<4;n++)
      #pragma unroll
      for (int r=0;r<4;r++) {
        const int row = m0 + wr*64 + m*16 + lg*4 + r;
        const int col = n0 + wc*64 + n*16 + lr;
        const size_t idx = (size_t)row*N + col;
        if constexpr (EPI==0) {
          ((unsigned short*)outp)[idx] = f2bf(acc[m][n][r]);
        } else if constexpr (EPI==1) {
          ((float*)outp)[idx] = acc[m][n][r] + aux[idx];
        } else {
          float g = acc[m][n][r];
          float u = bf2f(((unsigned short*)outp)[idx]);
          float sg = u / (1.0f + __expf(-u));
          ((unsigned short*)outp)[idx] = f2bf(sg * g);
        }
      }
}

// ------------- Flash attention (causal). q,k: bf16 [4096][2048]; vt: bf16 [b*2048][S] -------------
__global__ __launch_bounds__(256) void attn_kernel(const unsigned short* __restrict__ q,
                                                   const unsigned short* __restrict__ k,
                                                   const unsigned short* __restrict__ vt,
                                                   unsigned short* __restrict__ ao) {
  const int t = threadIdx.x, lane = t & 63, w = t >> 6;
  const int qt = blockIdx.x, bh = blockIdx.y;
  const int b = bh >> 4, h = bh & 15;
  const int lr = lane & 15, lg = lane >> 4;
  const int q0 = qt*64 + w*16;           // this wave's q-row start
  __shared__ unsigned short P[4][16*40]; // per-wave P tile, stride 40 (16B-aligned rows)
  unsigned short* pw = &P[w][0];

  short8 aq[4];
  {
    const unsigned short* qp = q + ((size_t)(b*SEQ + q0 + lr))*DIM + h*HDIM;
    #pragma unroll
    for (int c=0;c<4;c++) aq[c] = *(const short8*)(qp + c*32 + lg*8);
  }
  f32x4 accO[8] = {};
  float mrow[4], lrow[4];
  int rq[4];
  #pragma unroll
  for (int r=0;r<4;r++) { mrow[r] = -3.0e38f; lrow[r] = 0.0f; rq[r] = q0 + lg*4 + r; }
  const float scale = 0.08838834764831845f; // 1/sqrt(128)
  const size_t kbase = (size_t)(b*SEQ)*DIM + h*HDIM;
  const size_t vbase = (size_t)(bh*HDIM)*SEQ;
  const int kv_end = q0 + 16;             // causal: kv <= q0+15

  for (int kv0 = 0; kv0 < kv_end; kv0 += 32) {
    f32x4 sc[2] = {};
    #pragma unroll
    for (int blk=0;blk<2;blk++) {
      const unsigned short* kp = k + kbase + (size_t)(kv0 + blk*16 + lr)*DIM;
      #pragma unroll
      for (int c=0;c<4;c++) {
        short8 bk = *(const short8*)(kp + c*32 + lg*8);
        sc[blk] = __builtin_amdgcn_mfma_f32_16x16x32_bf16(aq[c], bk, sc[blk], 0,0,0);
      }
    }
    float fac[4];
    #pragma unroll
    for (int r=0;r<4;r++) {
      #pragma unroll
      for (int blk=0;blk<2;blk++) {
        float s = sc[blk][r] * scale;
        if (kv0 + blk*16 + lr > rq[r]) s = -1.0e30f;
        sc[blk][r] = s;
      }
      float pm = fmaxf(sc[0][r], sc[1][r]);
      #pragma unroll
      for (int x=1;x<16;x<<=1) pm = fmaxf(pm, __shfl_xor(pm, x));
      float mn = fmaxf(mrow[r], pm);
      fac[r] = __expf(mrow[r] - mn);
      float p0 = __expf(sc[0][r] - mn), p1 = __expf(sc[1][r] - mn);
      sc[0][r] = p0; sc[1][r] = p1;
      float ps = p0 + p1;
      #pragma unroll
      for (int x=1;x<16;x<<=1) ps += __shfl_xor(ps, x);
      lrow[r] = lrow[r]*fac[r] + ps;
      mrow[r] = mn;
    }
    #pragma unroll
    for (int n=0;n<8;n++)
      #pragma unroll
      for (int r=0;r<4;r++) accO[n][r] *= fac[r];
    // P -> LDS (bf16)
    #pragma unroll
    for (int blk=0;blk<2;blk++)
      #pragma unroll
      for (int r=0;r<4;r++)
        pw[(lg*4+r)*40 + blk*16 + lr] = f2bf(sc[blk][r]);
    short8 ap = *(const short8*)&pw[lr*40 + lg*8];
    #pragma unroll
    for (int n=0;n<8;n++) {
      short8 bv = *(const short8*)(vt + vbase + (size_t)(n*16 + lr)*SEQ + kv0 + lg*8);
      accO[n] = __builtin_amdgcn_mfma_f32_16x16x32_bf16(ap, bv, accO[n], 0,0,0);
    }
  }
  #pragma unroll
  for (int n=0;n<8;n++)
    #pragma unroll
    for (int r=0;r<4;r++)
      ao[((size_t)(b*SEQ + rq[r]))*DIM + h*HDIM + n*16 + lr] = f2bf(accO[n][r] / lrow[r]);
}

// ----------------------------------------------------------------------------
extern "C" void kernel_launch(void* const* d_in, const int* in_sizes, int n_in,
                              void* d_out, int out_size, void* d_ws, size_t ws_size,
                              hipStream_t stream) {
  (void)in_sizes; (void)n_in; (void)out_size; (void)ws_size;
  const float* x    = (const float*)d_in[0];
  const float* cosb = (const float*)d_in[1];
  const float* sinb = (const float*)d_in[2];
  // d_in[3] = mask (causal, implemented analytically)
  const float* anw  = (const float*)d_in[4];
  const float* fnw  = (const float*)d_in[5];
  const float* wq   = (const float*)d_in[6];
  const float* wk   = (const float*)d_in[7];
  const float* wv   = (const float*)d_in[8];
  const float* wo   = (const float*)d_in[9];
  const float* w1   = (const float*)d_in[10];
  const float* w2   = (const float*)d_in[11];
  const float* w3   = (const float*)d_in[12];

  char* ws = (char*)d_ws;
  const size_t SZ = 16777216; // 16 MiB unit (4096*2048 bf16)
  unsigned short* h   = (unsigned short*)(ws);
  unsigned short* qb  = (unsigned short*)(ws + 1*SZ);
  unsigned short* kb  = (unsigned short*)(ws + 2*SZ);
  unsigned short* vb  = (unsigned short*)(ws + 3*SZ);
  unsigned short* aob = (unsigned short*)(ws + 4*SZ);
  unsigned short* mid = qb;                 // [4096][8192] bf16, reuses q..ao (64 MiB)
  float* x1 = (float*)(ws + 5*SZ);          // 32 MiB fp32
  char* wt  = ws + 7*SZ;                    // 32 MiB weight/Vt scratch (sequential reuse)
  unsigned short* wqT = (unsigned short*)wt;
  unsigned short* wkT = (unsigned short*)(wt + 8388608);
  unsigned short* wvT = (unsigned short*)(wt + 2*8388608);
  unsigned short* vtb = (unsigned short*)wt;            // after QKV gemms
  unsigned short* woT = (unsigned short*)wt;            // after attention
  unsigned short* w1T = (unsigned short*)wt;            // 32 MiB
  unsigned short* w3T = (unsigned short*)wt;            // sequential reuse
  unsigned short* w2T = (unsigned short*)wt;

  dim3 b256(256);
  dim3 tb(32, 8);

  rmsnorm_kernel<<<dim3(MROWS), b256, 0, stream>>>(x, anw, h);

  transpose_w_kernel<<<dim3(64,64), tb, 0, stream>>>(wq, wqT, 2048, 2048);
  transpose_w_kernel<<<dim3(64,64), tb, 0, stream>>>(wk, wkT, 2048, 2048);
  transpose_w_kernel<<<dim3(64,64), tb, 0, stream>>>(wv, wvT, 2048, 2048);

  gemm_kernel<0><<<dim3(16,32), b256, 0, stream>>>(h, wqT, nullptr, qb, MROWS, 2048, 2048);
  gemm_kernel<0><<<dim3(16,32), b256, 0, stream>>>(h, wkT, nullptr, kb, MROWS, 2048, 2048);
  gemm_kernel<0><<<dim3(16,32), b256, 0, stream>>>(h, wvT, nullptr, vb, MROWS, 2048, 2048);

  rope_kernel<<<dim3(16384), b256, 0, stream>>>(qb, cosb, sinb);
  rope_kernel<<<dim3(16384), b256, 0, stream>>>(kb, cosb, sinb);

  transpose_v_kernel<<<dim3(64,64,2), tb, 0, stream>>>(vb, vtb);

  attn_kernel<<<dim3(32,32), b256, 0, stream>>>(qb, kb, vtb, aob);

  transpose_w_kernel<<<dim3(64,64), tb, 0, stream>>>(wo, woT, 2048, 2048);
  gemm_kernel<1><<<dim3(16,32), b256, 0, stream>>>(aob, woT, x, x1, MROWS, 2048, 2048);

  rmsnorm_kernel<<<dim3(MROWS), b256, 0, stream>>>(x1, fnw, h);

  // FFN: u = h@w1 -> mid (bf16); then g = h@w3 with fused silu(u)*g in-place.
  transpose_w_kernel<<<dim3(64,256), tb, 0, stream>>>(w1, w1T, 2048, 8192);
  gemm_kernel<0><<<dim3(64,32), b256, 0, stream>>>(h, w1T, nullptr, mid, MROWS, 8192, 2048);
  transpose_w_kernel<<<dim3(64,256), tb, 0, stream>>>(w3, w3T, 2048, 8192);
  gemm_kernel<3><<<dim3(64,32), b256, 0, stream>>>(h, w3T, nullptr, mid, MROWS, 8192, 2048);

  transpose_w_kernel<<<dim3(256,64), tb, 0, stream>>>(w2, w2T, 8192, 2048);
  gemm_kernel<1><<<dim3(16,32), b256, 0, stream>>>(mid, w2T, x1, (float*)d_out, MROWS, 2048, 8192);
}

// Round 3
// 1246.928 us; speedup vs baseline: 1.3377x; 1.2160x over previous
//
#include <hip/hip_runtime.h>

#define DIM 2048
#define HDIM 128
#define NH 16
#define SEQ 2048
#define BATCH 2
#define MROWS (BATCH*SEQ)   // 4096

typedef __attribute__((ext_vector_type(8))) short short8;
typedef __attribute__((ext_vector_type(4))) float f32x4;

__device__ __forceinline__ unsigned short f2bf(float f) {
  union { float f; unsigned u; } v; v.f = f;
  unsigned r = v.u + 0x7FFFu + ((v.u >> 16) & 1u);
  return (unsigned short)(r >> 16);
}
__device__ __forceinline__ float bf2f(unsigned short b) {
  union { unsigned u; float f; } v; v.u = ((unsigned)b) << 16;
  return v.f;
}

__device__ __forceinline__ void gload16(const void* g, void* l) {
  __builtin_amdgcn_global_load_lds((const __attribute__((address_space(1))) unsigned int*)g,
                                   (__attribute__((address_space(3))) unsigned int*)l,
                                   16, 0, 0);
}

// ---------------- RMSNorm: fp32 [rows][2048] -> bf16 ----------------
__global__ __launch_bounds__(256) void rmsnorm_kernel(const float* __restrict__ x,
                                                      const float* __restrict__ w,
                                                      unsigned short* __restrict__ out) {
  const int row = blockIdx.x;
  const int t = threadIdx.x;
  const float* xr = x + (size_t)row * DIM;
  float4 v0 = ((const float4*)xr)[t*2];
  float4 v1 = ((const float4*)xr)[t*2+1];
  float ss = v0.x*v0.x + v0.y*v0.y + v0.z*v0.z + v0.w*v0.w
           + v1.x*v1.x + v1.y*v1.y + v1.z*v1.z + v1.w*v1.w;
  #pragma unroll
  for (int i = 1; i < 64; i <<= 1) ss += __shfl_xor(ss, i);
  __shared__ float red[4];
  if ((t & 63) == 0) red[t >> 6] = ss;
  __syncthreads();
  float sum = red[0] + red[1] + red[2] + red[3];
  float sc = rsqrtf(sum * (1.0f/DIM) + 1e-6f);
  const float* wr = w + t*8;
  unsigned short ob[8];
  ob[0] = f2bf(v0.x*sc*wr[0]); ob[1] = f2bf(v0.y*sc*wr[1]);
  ob[2] = f2bf(v0.z*sc*wr[2]); ob[3] = f2bf(v0.w*sc*wr[3]);
  ob[4] = f2bf(v1.x*sc*wr[4]); ob[5] = f2bf(v1.y*sc*wr[5]);
  ob[6] = f2bf(v1.z*sc*wr[6]); ob[7] = f2bf(v1.w*sc*wr[7]);
  uint4 pk;
  pk.x = (unsigned)ob[0] | ((unsigned)ob[1] << 16);
  pk.y = (unsigned)ob[2] | ((unsigned)ob[3] << 16);
  pk.z = (unsigned)ob[4] | ((unsigned)ob[5] << 16);
  pk.w = (unsigned)ob[6] | ((unsigned)ob[7] << 16);
  *((uint4*)(out + (size_t)row*DIM + t*8)) = pk;
}

// ------------- Weight transpose: fp32 [K][N] -> bf16 [N][K] -------------
__global__ __launch_bounds__(256) void transpose_w_kernel(const float* __restrict__ W,
                                                          unsigned short* __restrict__ Wt,
                                                          int K, int N) {
  __shared__ float tile[32][33];
  const int k0 = blockIdx.x*32, n0 = blockIdx.y*32;
  const int tx = threadIdx.x, ty = threadIdx.y;
  #pragma unroll
  for (int i=0;i<4;i++) tile[ty+i*8][tx] = W[(size_t)(k0+ty+i*8)*N + n0+tx];
  __syncthreads();
  #pragma unroll
  for (int i=0;i<4;i++) Wt[(size_t)(n0+ty+i*8)*K + k0+tx] = f2bf(tile[tx][ty+i*8]);
}

// ------------- V transpose (bf16): [b*S][2048] -> [b*2048][S] -------------
__global__ __launch_bounds__(256) void transpose_v_kernel(const unsigned short* __restrict__ v,
                                                          unsigned short* __restrict__ vt) {
  __shared__ unsigned short tile[32][33];
  const int b = blockIdx.z;
  const int s0 = blockIdx.x*32, c0 = blockIdx.y*32;
  const int tx = threadIdx.x, ty = threadIdx.y;
  #pragma unroll
  for (int i=0;i<4;i++) tile[ty+i*8][tx] = v[((size_t)(b*SEQ + s0+ty+i*8))*DIM + c0+tx];
  __syncthreads();
  #pragma unroll
  for (int i=0;i<4;i++) vt[((size_t)(b*DIM + c0+ty+i*8))*SEQ + s0+tx] = tile[tx][ty+i*8];
}

// ------------- RoPE in-place on bf16 [4096][2048] -------------
__global__ __launch_bounds__(256) void rope_kernel(unsigned short* __restrict__ qk,
                                                   const float* __restrict__ cosb,
                                                   const float* __restrict__ sinb) {
  const size_t idx = (size_t)blockIdx.x * 256 + threadIdx.x; // pair index
  const int d = (int)(idx & 63);
  const int h = (int)((idx >> 6) & 15);
  const int row = (int)(idx >> 10);       // 0..4095
  const int s = row & (SEQ-1);
  const size_t base = (size_t)row * DIM + h*HDIM + d;
  float a  = bf2f(qk[base]);
  float bq = bf2f(qk[base+64]);
  float c1 = cosb[s*HDIM + d],    s1 = sinb[s*HDIM + d];
  float c2 = cosb[s*HDIM + d+64], s2 = sinb[s*HDIM + d+64];
  qk[base]    = f2bf(a*c1 - bq*s1);
  qk[base+64] = f2bf(bq*c2 + a*s2);
}

// ------------- GEMM: C[M][N] = A[M][K](bf16) @ Bt[N][K]^T (bf16) -------------
// EPI 0: bf16 out.  EPI 1: fp32 out = acc + aux.
// EPI 3: out(bf16, in-place u) = silu(u) * acc.
template<int EPI>
__global__ __launch_bounds__(256) void gemm_kernel(const unsigned short* __restrict__ A,
                                                   const unsigned short* __restrict__ Bt,
                                                   const float* __restrict__ aux,
                                                   void* outp,
                                                   int M, int N, int K) {
  const int t = threadIdx.x;
  const int lane = t & 63, w = t >> 6;
  // bijective XCD-chunked swizzle (nwg % 8 == 0 for all our grids; gridDim.x pow2)
  const int bid0 = blockIdx.y * gridDim.x + blockIdx.x;
  const int nwg = gridDim.x * gridDim.y;
  const int s = ((bid0 & 7) * (nwg >> 3)) + (bid0 >> 3);
  const int gxsh = 31 - __clz(gridDim.x);
  const int bx = s & (gridDim.x - 1);
  const int by = s >> gxsh;
  const int m0 = by * 128, n0 = bx * 128;
  const int wr = w >> 1, wc = w & 1;
  __shared__ unsigned short As[128*32];
  __shared__ unsigned short Bs[128*32];
  f32x4 acc[4][4] = {};
  const int srow = lane >> 2;        // staging row within 16-row chunk
  const int scol = (lane & 3) * 8;   // staging k offset
  const int lr = lane & 15, lg = lane >> 4;

  for (int k0 = 0; k0 < K; k0 += 32) {
    #pragma unroll
    for (int i = 0; i < 2; i++) {
      const int chunk = w*2 + i;
      const int row = chunk*16 + srow;
      gload16(&A [(size_t)(m0+row)*K + k0 + scol], &As [chunk*512]);
      gload16(&Bt[(size_t)(n0+row)*K + k0 + scol], &Bs [chunk*512]);
    }
    __syncthreads();   // drains vmcnt -> tiles ready
    short8 af[4], bfr[4];
    #pragma unroll
    for (int m=0;m<4;m++) af[m]  = *(const short8*)&As [(wr*64 + m*16 + lr)*32 + lg*8];
    #pragma unroll
    for (int n=0;n<4;n++) bfr[n] = *(const short8*)&Bs [(wc*64 + n*16 + lr)*32 + lg*8];
    #pragma unroll
    for (int m=0;m<4;m++)
      #pragma unroll
      for (int n=0;n<4;n++)
        acc[m][n] = __builtin_amdgcn_mfma_f32_16x16x32_bf16(af[m], bfr[n], acc[m][n], 0,0,0);
    __syncthreads();   // all waves done reading before next stage
  }

  #pragma unroll
  for (int m=0;m<4;m++)
    #pragma unroll
    for (int n=0;n<4;n++)
      #pragma unroll
      for (int r=0;r<4;r++) {
        const int row = m0 + wr*64 + m*16 + lg*4 + r;
        const int col = n0 + wc*64 + n*16 + lr;
        const size_t idx = (size_t)row*N + col;
        if constexpr (EPI==0) {
          ((unsigned short*)outp)[idx] = f2bf(acc[m][n][r]);
        } else if constexpr (EPI==1) {
          ((float*)outp)[idx] = acc[m][n][r] + aux[idx];
        } else {
          float g = acc[m][n][r];
          float u = bf2f(((unsigned short*)outp)[idx]);
          float sg = u / (1.0f + __expf(-u));
          ((unsigned short*)outp)[idx] = f2bf(sg * g);
        }
      }
}

// ------------- Flash attention (causal), LDS-staged K/Vt tiles -------------
// q,k: bf16 [4096][2048]; vt: bf16 [bh*128][SEQ]
// Block: 4 waves, 64 q-rows (wave w owns rows q0=qt*64+16w..+15).
// Per kv-step (32): stage K tile (32x128, XOR-swizzled) + Vt tile (128x32, linear)
// into LDS via global_load_lds; all 4 waves share them.
__global__ __launch_bounds__(256) void attn_kernel(const unsigned short* __restrict__ q,
                                                   const unsigned short* __restrict__ k,
                                                   const unsigned short* __restrict__ vt,
                                                   unsigned short* __restrict__ ao) {
  const int t = threadIdx.x, lane = t & 63, w = t >> 6;
  const int qt = (int)gridDim.x - 1 - (int)blockIdx.x;   // longest-first dispatch
  const int bh = blockIdx.y;
  const int b = bh >> 4, h = bh & 15;
  const int lr = lane & 15, lg = lane >> 4;
  const int q0 = qt*64 + w*16;           // this wave's q-row start

  __shared__ unsigned short Kb[32*128];  // 8 KB, swizzled: short s' holds col s'^((row&7)<<3)
  __shared__ unsigned short Vb[128*32];  // 8 KB, linear: [d][kv]
  __shared__ unsigned short P[4][16*40]; // per-wave P tile, stride 40 (16B-aligned rows)
  unsigned short* pw = &P[w][0];

  short8 aq[4];
  {
    const unsigned short* qp = q + ((size_t)(b*SEQ + q0 + lr))*DIM + h*HDIM;
    #pragma unroll
    for (int c=0;c<4;c++) aq[c] = *(const short8*)(qp + c*32 + lg*8);
  }
  f32x4 accO[8] = {};
  float mrow[4], lrow[4];
  int rq[4];
  #pragma unroll
  for (int r=0;r<4;r++) { mrow[r] = -3.0e38f; lrow[r] = 0.0f; rq[r] = q0 + lg*4 + r; }
  const float scale = 0.08838834764831845f; // 1/sqrt(128)
  const unsigned short* kg = k + (size_t)(b*SEQ)*DIM + h*HDIM;
  const unsigned short* vg = vt + (size_t)(bh*HDIM)*SEQ;
  const int kv_end_w = q0 + 16;          // causal: this wave needs kv < q0+16
  const int KV_END = qt*64 + 64;         // block-uniform loop bound

  // staging addresses (per thread), invariant across kv-steps
  const int krow_i[2] = { (t>>4), 16 + (t>>4) };            // K rows per issue
  const int kcs = (((t & 15) << 3) ^ (((t>>4)&7) << 3));    // shorts: swizzled src col
  const int vrow_i[2] = { (t>>2), 64 + (t>>2) };            // Vt rows per issue
  const int vcs = (t & 3) << 3;

  for (int kv0 = 0; kv0 < KV_END; kv0 += 32) {
    // ---- stage K (swizzled source -> linear LDS) and Vt (linear) ----
    #pragma unroll
    for (int i=0;i<2;i++) {
      gload16(kg + (size_t)(kv0 + krow_i[i])*DIM + kcs, &Kb[i*2048 + w*512]);
      gload16(vg + (size_t)vrow_i[i]*SEQ + kv0 + vcs,   &Vb[i*2048 + w*512]);
    }
    __syncthreads();   // tiles ready

    if (kv0 < kv_end_w) {
      f32x4 sc[2] = {};
      #pragma unroll
      for (int blk=0;blk<2;blk++) {
        const int krow = blk*16 + lr;
        const unsigned short* kp = &Kb[krow*128];
        const int sw = (krow & 7) << 3;
        #pragma unroll
        for (int c=0;c<4;c++) {
          short8 bk = *(const short8*)(kp + ((c*32 + lg*8) ^ sw));
          sc[blk] = __builtin_amdgcn_mfma_f32_16x16x32_bf16(aq[c], bk, sc[blk], 0,0,0);
        }
      }
      float fac[4];
      #pragma unroll
      for (int r=0;r<4;r++) {
        #pragma unroll
        for (int blk=0;blk<2;blk++) {
          float s = sc[blk][r] * scale;
          if (kv0 + blk*16 + lr > rq[r]) s = -1.0e30f;
          sc[blk][r] = s;
        }
        float pm = fmaxf(sc[0][r], sc[1][r]);
        #pragma unroll
        for (int x=1;x<16;x<<=1) pm = fmaxf(pm, __shfl_xor(pm, x));
        float mn = fmaxf(mrow[r], pm);
        fac[r] = __expf(mrow[r] - mn);
        float p0 = __expf(sc[0][r] - mn), p1 = __expf(sc[1][r] - mn);
        sc[0][r] = p0; sc[1][r] = p1;
        float ps = p0 + p1;
        #pragma unroll
        for (int x=1;x<16;x<<=1) ps += __shfl_xor(ps, x);
        lrow[r] = lrow[r]*fac[r] + ps;
        mrow[r] = mn;
      }
      #pragma unroll
      for (int n=0;n<8;n++)
        #pragma unroll
        for (int r=0;r<4;r++) accO[n][r] *= fac[r];
      // P -> LDS (bf16)
      #pragma unroll
      for (int blk=0;blk<2;blk++)
        #pragma unroll
        for (int r=0;r<4;r++)
          pw[(lg*4+r)*40 + blk*16 + lr] = f2bf(sc[blk][r]);
      short8 ap = *(const short8*)&pw[lr*40 + lg*8];
      #pragma unroll
      for (int n=0;n<8;n++) {
        short8 bv = *(const short8*)&Vb[(n*16 + lr)*32 + lg*8];
        accO[n] = __builtin_amdgcn_mfma_f32_16x16x32_bf16(ap, bv, accO[n], 0,0,0);
      }
    }
    __syncthreads();   // all waves done reading before next stage
  }
  #pragma unroll
  for (int n=0;n<8;n++)
    #pragma unroll
    for (int r=0;r<4;r++)
      ao[((size_t)(b*SEQ + rq[r]))*DIM + h*HDIM + n*16 + lr] = f2bf(accO[n][r] / lrow[r]);
}

// ----------------------------------------------------------------------------
extern "C" void kernel_launch(void* const* d_in, const int* in_sizes, int n_in,
                              void* d_out, int out_size, void* d_ws, size_t ws_size,
                              hipStream_t stream) {
  (void)in_sizes; (void)n_in; (void)out_size; (void)ws_size;
  const float* x    = (const float*)d_in[0];
  const float* cosb = (const float*)d_in[1];
  const float* sinb = (const float*)d_in[2];
  // d_in[3] = mask (causal, implemented analytically)
  const float* anw  = (const float*)d_in[4];
  const float* fnw  = (const float*)d_in[5];
  const float* wq   = (const float*)d_in[6];
  const float* wk   = (const float*)d_in[7];
  const float* wv   = (const float*)d_in[8];
  const float* wo   = (const float*)d_in[9];
  const float* w1   = (const float*)d_in[10];
  const float* w2   = (const float*)d_in[11];
  const float* w3   = (const float*)d_in[12];

  char* ws = (char*)d_ws;
  const size_t SZ = 16777216; // 16 MiB unit (4096*2048 bf16)
  unsigned short* h   = (unsigned short*)(ws);
  unsigned short* qb  = (unsigned short*)(ws + 1*SZ);
  unsigned short* kb  = (unsigned short*)(ws + 2*SZ);
  unsigned short* vb  = (unsigned short*)(ws + 3*SZ);
  unsigned short* aob = (unsigned short*)(ws + 4*SZ);
  unsigned short* mid = qb;                 // [4096][8192] bf16, reuses q..ao (64 MiB)
  float* x1 = (float*)(ws + 5*SZ);          // 32 MiB fp32
  char* wt  = ws + 7*SZ;                    // 32 MiB weight/Vt scratch (sequential reuse)
  unsigned short* wqT = (unsigned short*)wt;
  unsigned short* wkT = (unsigned short*)(wt + 8388608);
  unsigned short* wvT = (unsigned short*)(wt + 2*8388608);
  unsigned short* vtb = (unsigned short*)wt;            // after QKV gemms
  unsigned short* woT = (unsigned short*)wt;            // after attention
  unsigned short* w1T = (unsigned short*)wt;            // 32 MiB
  unsigned short* w3T = (unsigned short*)wt;            // sequential reuse
  unsigned short* w2T = (unsigned short*)wt;

  dim3 b256(256);
  dim3 tb(32, 8);

  rmsnorm_kernel<<<dim3(MROWS), b256, 0, stream>>>(x, anw, h);

  transpose_w_kernel<<<dim3(64,64), tb, 0, stream>>>(wq, wqT, 2048, 2048);
  transpose_w_kernel<<<dim3(64,64), tb, 0, stream>>>(wk, wkT, 2048, 2048);
  transpose_w_kernel<<<dim3(64,64), tb, 0, stream>>>(wv, wvT, 2048, 2048);

  gemm_kernel<0><<<dim3(16,32), b256, 0, stream>>>(h, wqT, nullptr, qb, MROWS, 2048, 2048);
  gemm_kernel<0><<<dim3(16,32), b256, 0, stream>>>(h, wkT, nullptr, kb, MROWS, 2048, 2048);
  gemm_kernel<0><<<dim3(16,32), b256, 0, stream>>>(h, wvT, nullptr, vb, MROWS, 2048, 2048);

  rope_kernel<<<dim3(16384), b256, 0, stream>>>(qb, cosb, sinb);
  rope_kernel<<<dim3(16384), b256, 0, stream>>>(kb, cosb, sinb);

  transpose_v_kernel<<<dim3(64,64,2), tb, 0, stream>>>(vb, vtb);

  attn_kernel<<<dim3(32,32), b256, 0, stream>>>(qb, kb, vtb, aob);

  transpose_w_kernel<<<dim3(64,64), tb, 0, stream>>>(wo, woT, 2048, 2048);
  gemm_kernel<1><<<dim3(16,32), b256, 0, stream>>>(aob, woT, x, x1, MROWS, 2048, 2048);

  rmsnorm_kernel<<<dim3(MROWS), b256, 0, stream>>>(x1, fnw, h);

  // FFN: u = h@w1 -> mid (bf16); then g = h@w3 with fused silu(u)*g in-place.
  transpose_w_kernel<<<dim3(64,256), tb, 0, stream>>>(w1, w1T, 2048, 8192);
  gemm_kernel<0><<<dim3(64,32), b256, 0, stream>>>(h, w1T, nullptr, mid, MROWS, 8192, 2048);
  transpose_w_kernel<<<dim3(64,256), tb, 0, stream>>>(w3, w3T, 2048, 8192);
  gemm_kernel<3><<<dim3(64,32), b256, 0, stream>>>(h, w3T, nullptr, mid, MROWS, 8192, 2048);

  transpose_w_kernel<<<dim3(256,64), tb, 0, stream>>>(w2, w2T, 8192, 2048);
  gemm_kernel<1><<<dim3(16,32), b256, 0, stream>>>(mid, w2T, x1, (float*)d_out, MROWS, 2048, 8192);
}

// Round 4
// 1028.510 us; speedup vs baseline: 1.6218x; 1.2124x over previous
//
#include <hip/hip_runtime.h>

#define DIM 2048
#define HDIM 128
#define NH 16
#define SEQ 2048
#define BATCH 2
#define MROWS (BATCH*SEQ)   // 4096
#define QKP 6144            // qkv row pitch (q|k|v concatenated)

typedef __attribute__((ext_vector_type(8))) short short8;
typedef __attribute__((ext_vector_type(4))) float f32x4;

__device__ __forceinline__ unsigned short f2bf(float f) {
  union { float f; unsigned u; } v; v.f = f;
  unsigned r = v.u + 0x7FFFu + ((v.u >> 16) & 1u);
  return (unsigned short)(r >> 16);
}
__device__ __forceinline__ float bf2f(unsigned short b) {
  union { unsigned u; float f; } v; v.u = ((unsigned)b) << 16;
  return v.f;
}

__device__ __forceinline__ void gload16(const void* g, void* l) {
  __builtin_amdgcn_global_load_lds((const __attribute__((address_space(1))) unsigned int*)g,
                                   (__attribute__((address_space(3))) unsigned int*)l,
                                   16, 0, 0);
}

// ---------------- RMSNorm: fp32 [rows][2048] -> bf16 ----------------
__global__ __launch_bounds__(256) void rmsnorm_kernel(const float* __restrict__ x,
                                                      const float* __restrict__ w,
                                                      unsigned short* __restrict__ out) {
  const int row = blockIdx.x;
  const int t = threadIdx.x;
  const float* xr = x + (size_t)row * DIM;
  float4 v0 = ((const float4*)xr)[t*2];
  float4 v1 = ((const float4*)xr)[t*2+1];
  float ss = v0.x*v0.x + v0.y*v0.y + v0.z*v0.z + v0.w*v0.w
           + v1.x*v1.x + v1.y*v1.y + v1.z*v1.z + v1.w*v1.w;
  #pragma unroll
  for (int i = 1; i < 64; i <<= 1) ss += __shfl_xor(ss, i);
  __shared__ float red[4];
  if ((t & 63) == 0) red[t >> 6] = ss;
  __syncthreads();
  float sum = red[0] + red[1] + red[2] + red[3];
  float sc = rsqrtf(sum * (1.0f/DIM) + 1e-6f);
  const float* wr = w + t*8;
  unsigned short ob[8];
  ob[0] = f2bf(v0.x*sc*wr[0]); ob[1] = f2bf(v0.y*sc*wr[1]);
  ob[2] = f2bf(v0.z*sc*wr[2]); ob[3] = f2bf(v0.w*sc*wr[3]);
  ob[4] = f2bf(v1.x*sc*wr[4]); ob[5] = f2bf(v1.y*sc*wr[5]);
  ob[6] = f2bf(v1.z*sc*wr[6]); ob[7] = f2bf(v1.w*sc*wr[7]);
  uint4 pk;
  pk.x = (unsigned)ob[0] | ((unsigned)ob[1] << 16);
  pk.y = (unsigned)ob[2] | ((unsigned)ob[3] << 16);
  pk.z = (unsigned)ob[4] | ((unsigned)ob[5] << 16);
  pk.w = (unsigned)ob[6] | ((unsigned)ob[7] << 16);
  *((uint4*)(out + (size_t)row*DIM + t*8)) = pk;
}

// ------------- Weight transpose: fp32 [K][N] -> bf16 [N][K] -------------
__global__ __launch_bounds__(256) void transpose_w_kernel(const float* __restrict__ W,
                                                          unsigned short* __restrict__ Wt,
                                                          int K, int N) {
  __shared__ float tile[32][33];
  const int k0 = blockIdx.x*32, n0 = blockIdx.y*32;
  const int tx = threadIdx.x, ty = threadIdx.y;
  #pragma unroll
  for (int i=0;i<4;i++) tile[ty+i*8][tx] = W[(size_t)(k0+ty+i*8)*N + n0+tx];
  __syncthreads();
  #pragma unroll
  for (int i=0;i<4;i++) Wt[(size_t)(n0+ty+i*8)*K + k0+tx] = f2bf(tile[tx][ty+i*8]);
}

// ------------- V transpose (bf16): [b*S][vpitch cols 0..2047] -> [b*2048][S] -------------
__global__ __launch_bounds__(256) void transpose_v_kernel(const unsigned short* __restrict__ v,
                                                          int vpitch,
                                                          unsigned short* __restrict__ vt) {
  __shared__ unsigned short tile[32][33];
  const int b = blockIdx.z;
  const int s0 = blockIdx.x*32, c0 = blockIdx.y*32;
  const int tx = threadIdx.x, ty = threadIdx.y;
  #pragma unroll
  for (int i=0;i<4;i++) tile[ty+i*8][tx] = v[((size_t)(b*SEQ + s0+ty+i*8))*vpitch + c0+tx];
  __syncthreads();
  #pragma unroll
  for (int i=0;i<4;i++) vt[((size_t)(b*DIM + c0+ty+i*8))*SEQ + s0+tx] = tile[tx][ty+i*8];
}

// ------------- RoPE in-place on q|k halves of qkv buffer [4096][QKP] -------------
__global__ __launch_bounds__(256) void rope_qk(unsigned short* __restrict__ qk,
                                               const float* __restrict__ cosb,
                                               const float* __restrict__ sinb) {
  const size_t idx = (size_t)blockIdx.x * 256 + threadIdx.x; // pair index
  const int d = (int)(idx & 63);
  const int h = (int)((idx >> 6) & 31);   // 32 head-slots: q heads 0-15, k heads 16-31
  const int row = (int)(idx >> 11);       // 0..4095
  const int s = row & (SEQ-1);
  const size_t base = (size_t)row * QKP + h*HDIM + d;
  float a  = bf2f(qk[base]);
  float bq = bf2f(qk[base+64]);
  float c1 = cosb[s*HDIM + d],    s1 = sinb[s*HDIM + d];
  float c2 = cosb[s*HDIM + d+64], s2 = sinb[s*HDIM + d+64];
  qk[base]    = f2bf(a*c1 - bq*s1);
  qk[base+64] = f2bf(bq*c2 + a*s2);
}

// ------------- Pipelined GEMM: C[M][N] = A[M][K](bf16) @ Bt[N][K]^T -------------
// BN=256, BK=32, 8 waves (2M x 4N). Ring of 4 LDS K-tile slots, depth-3 prefetch,
// counted vmcnt (T3+T4), read-swizzled LDS (T2-class, 2-way = free), setprio (T5).
// EPI 0: bf16 out. EPI 1: fp32 out = acc + aux. EPI 3: out(bf16,in-place u)=silu(u)*acc.
template<int BM, int EPI>
__global__ __launch_bounds__(512, 2) void gemm_pipe(const unsigned short* __restrict__ A,
                                                    const unsigned short* __restrict__ Bt,
                                                    const float* __restrict__ aux,
                                                    void* __restrict__ outp,
                                                    int M, int N, int K) {
  constexpr int MF = BM / 32;          // per-wave m-fragments (8 or 4)
  constexpr int ASLOT = BM * 32;       // shorts per A region of a slot
  constexpr int SLOT = (BM + 256) * 32;
  extern __shared__ unsigned short ldsd[];
  const int tid = threadIdx.x, l = tid & 63, wid = tid >> 6;
  const int wm = wid >> 2, wn = wid & 3;
  const int lr = l & 15, lg = l >> 4;

  // bijective XCD-chunked swizzle on 1-D grid (nwg % 8 == 0 for all our grids)
  const int nbx = N >> 8;
  const int nwg = gridDim.x;
  const int sb = ((int)blockIdx.x & 7) * (nwg >> 3) + ((int)blockIdx.x >> 3);
  const int bx = sb % nbx, by = sb / nbx;
  const int m0 = by * BM, n0 = bx * 256;

  // staging per-lane constants (global source pre-swizzle, involution on 16B slots)
  const int swz  = (((l & 3) ^ ((l >> 3) & 3)) << 3);  // shorts
  const int rsub = l >> 2;                              // 0..15

  // fragment read offsets (shorts) within a slot; swizzled to match staging
  const int kx = ((lg ^ ((lr >> 1) & 3)) << 3);
  int aoff[MF];
  #pragma unroll
  for (int mf = 0; mf < MF; mf++) aoff[mf] = (wm*(BM/2) + mf*16 + lr) * 32 + kx;
  int boff[4];
  #pragma unroll
  for (int nf = 0; nf < 4; nf++) boff[nf] = ASLOT + (wn*64 + nf*16 + lr) * 32 + kx;

  f32x4 acc[MF][4] = {};
  const int nt = K >> 5;

  auto STAGE = [&](int tt) {
    unsigned short* sA = ldsd + (tt & 3) * SLOT;
    unsigned short* sB = sA + ASLOT;
    const int k0 = tt << 5;
    #pragma unroll
    for (int c = 0; c < 2; c++) {
      const int rb = (c*8 + wid) * 16;
      gload16(Bt + (size_t)(n0 + rb + rsub) * K + k0 + swz, sB + rb*32);
    }
    if constexpr (BM == 256) {
      #pragma unroll
      for (int c = 0; c < 2; c++) {
        const int rb = (c*8 + wid) * 16;
        gload16(A + (size_t)(m0 + rb + rsub) * K + k0 + swz, sA + rb*32);
      }
    } else {
      const int rb = wid * 16;
      gload16(A + (size_t)(m0 + rb + rsub) * K + k0 + swz, sA + rb*32);
    }
  };

  STAGE(0); STAGE(1); STAGE(2);

  for (int tt = 0; tt < nt; ++tt) {
    if (tt + 3 < nt) {
      STAGE(tt + 3);    // writes slot (tt-1)&3: reads of tile tt-1 finished last iter
      // counted wait: confirms tile tt+1 landed (tile tt confirmed last iter)
      if constexpr (BM == 256) asm volatile("s_waitcnt vmcnt(8)" ::: "memory");
      else                     asm volatile("s_waitcnt vmcnt(6)" ::: "memory");
    } else {
      asm volatile("s_waitcnt vmcnt(0)" ::: "memory");
    }
    __builtin_amdgcn_s_barrier();
    const unsigned short* slot = ldsd + (tt & 3) * SLOT;
    short8 af[MF], bfv[4];
    #pragma unroll
    for (int mf = 0; mf < MF; mf++) af[mf] = *(const short8*)&slot[aoff[mf]];
    #pragma unroll
    for (int nf = 0; nf < 4; nf++) bfv[nf] = *(const short8*)&slot[boff[nf]];
    __builtin_amdgcn_s_setprio(1);
    #pragma unroll
    for (int mf = 0; mf < MF; mf++)
      #pragma unroll
      for (int nf = 0; nf < 4; nf++)
        acc[mf][nf] = __builtin_amdgcn_mfma_f32_16x16x32_bf16(af[mf], bfv[nf], acc[mf][nf], 0, 0, 0);
    __builtin_amdgcn_s_setprio(0);
    __builtin_amdgcn_s_barrier();  // all waves done reading slot tt before next overwrite
  }

  #pragma unroll
  for (int mf = 0; mf < MF; mf++)
    #pragma unroll
    for (int nf = 0; nf < 4; nf++)
      #pragma unroll
      for (int r = 0; r < 4; r++) {
        const int row = m0 + wm*(BM/2) + mf*16 + lg*4 + r;
        const int col = n0 + wn*64 + nf*16 + lr;
        const size_t idx = (size_t)row * N + col;
        if constexpr (EPI == 0) {
          ((unsigned short*)outp)[idx] = f2bf(acc[mf][nf][r]);
        } else if constexpr (EPI == 1) {
          ((float*)outp)[idx] = acc[mf][nf][r] + aux[idx];
        } else {
          float g = acc[mf][nf][r];
          float u = bf2f(((unsigned short*)outp)[idx]);
          float sg = u / (1.0f + __expf(-u));
          ((unsigned short*)outp)[idx] = f2bf(sg * g);
        }
      }
}

// ------------- Flash attention (causal), LDS-staged K/Vt tiles -------------
// q,k: bf16 [4096][QKP]; vt: bf16 [bh*128][SEQ]
__global__ __launch_bounds__(256) void attn_kernel(const unsigned short* __restrict__ q,
                                                   const unsigned short* __restrict__ k,
                                                   const unsigned short* __restrict__ vt,
                                                   unsigned short* __restrict__ ao) {
  const int t = threadIdx.x, lane = t & 63, w = t >> 6;
  const int qt = (int)gridDim.x - 1 - (int)blockIdx.x;   // longest-first dispatch
  const int bh = blockIdx.y;
  const int b = bh >> 4, h = bh & 15;
  const int lr = lane & 15, lg = lane >> 4;
  const int q0 = qt*64 + w*16;           // this wave's q-row start

  __shared__ unsigned short Kb[32*128];  // 8 KB, swizzled
  __shared__ unsigned short Vb[128*32];  // 8 KB, linear: [d][kv]
  __shared__ unsigned short P[4][16*40];
  unsigned short* pw = &P[w][0];

  short8 aq[4];
  {
    const unsigned short* qp = q + ((size_t)(b*SEQ + q0 + lr))*QKP + h*HDIM;
    #pragma unroll
    for (int c=0;c<4;c++) aq[c] = *(const short8*)(qp + c*32 + lg*8);
  }
  f32x4 accO[8] = {};
  float mrow[4], lrow[4];
  int rq[4];
  #pragma unroll
  for (int r=0;r<4;r++) { mrow[r] = -3.0e38f; lrow[r] = 0.0f; rq[r] = q0 + lg*4 + r; }
  const float scale = 0.08838834764831845f; // 1/sqrt(128)
  const unsigned short* kg = k + (size_t)(b*SEQ)*QKP + h*HDIM;
  const unsigned short* vg = vt + (size_t)(bh*HDIM)*SEQ;
  const int kv_end_w = q0 + 16;
  const int KV_END = qt*64 + 64;

  const int krow_i[2] = { (t>>4), 16 + (t>>4) };
  const int kcs = (((t & 15) << 3) ^ (((t>>4)&7) << 3));
  const int vrow_i[2] = { (t>>2), 64 + (t>>2) };
  const int vcs = (t & 3) << 3;

  for (int kv0 = 0; kv0 < KV_END; kv0 += 32) {
    #pragma unroll
    for (int i=0;i<2;i++) {
      gload16(kg + (size_t)(kv0 + krow_i[i])*QKP + kcs, &Kb[i*2048 + w*512]);
      gload16(vg + (size_t)vrow_i[i]*SEQ + kv0 + vcs,   &Vb[i*2048 + w*512]);
    }
    __syncthreads();

    if (kv0 < kv_end_w) {
      f32x4 sc[2] = {};
      #pragma unroll
      for (int blk=0;blk<2;blk++) {
        const int krow = blk*16 + lr;
        const unsigned short* kp = &Kb[krow*128];
        const int sw = (krow & 7) << 3;
        #pragma unroll
        for (int c=0;c<4;c++) {
          short8 bk = *(const short8*)(kp + ((c*32 + lg*8) ^ sw));
          sc[blk] = __builtin_amdgcn_mfma_f32_16x16x32_bf16(aq[c], bk, sc[blk], 0,0,0);
        }
      }
      float fac[4];
      #pragma unroll
      for (int r=0;r<4;r++) {
        #pragma unroll
        for (int blk=0;blk<2;blk++) {
          float s = sc[blk][r] * scale;
          if (kv0 + blk*16 + lr > rq[r]) s = -1.0e30f;
          sc[blk][r] = s;
        }
        float pm = fmaxf(sc[0][r], sc[1][r]);
        #pragma unroll
        for (int x=1;x<16;x<<=1) pm = fmaxf(pm, __shfl_xor(pm, x));
        float mn = fmaxf(mrow[r], pm);
        fac[r] = __expf(mrow[r] - mn);
        float p0 = __expf(sc[0][r] - mn), p1 = __expf(sc[1][r] - mn);
        sc[0][r] = p0; sc[1][r] = p1;
        float ps = p0 + p1;
        #pragma unroll
        for (int x=1;x<16;x<<=1) ps += __shfl_xor(ps, x);
        lrow[r] = lrow[r]*fac[r] + ps;
        mrow[r] = mn;
      }
      #pragma unroll
      for (int n=0;n<8;n++)
        #pragma unroll
        for (int r=0;r<4;r++) accO[n][r] *= fac[r];
      #pragma unroll
      for (int blk=0;blk<2;blk++)
        #pragma unroll
        for (int r=0;r<4;r++)
          pw[(lg*4+r)*40 + blk*16 + lr] = f2bf(sc[blk][r]);
      short8 ap = *(const short8*)&pw[lr*40 + lg*8];
      #pragma unroll
      for (int n=0;n<8;n++) {
        short8 bv = *(const short8*)&Vb[(n*16 + lr)*32 + lg*8];
        accO[n] = __builtin_amdgcn_mfma_f32_16x16x32_bf16(ap, bv, accO[n], 0,0,0);
      }
    }
    __syncthreads();
  }
  #pragma unroll
  for (int n=0;n<8;n++)
    #pragma unroll
    for (int r=0;r<4;r++)
      ao[((size_t)(b*SEQ + rq[r]))*DIM + h*HDIM + n*16 + lr] = f2bf(accO[n][r] / lrow[r]);
}

// ----------------------------------------------------------------------------
extern "C" void kernel_launch(void* const* d_in, const int* in_sizes, int n_in,
                              void* d_out, int out_size, void* d_ws, size_t ws_size,
                              hipStream_t stream) {
  (void)in_sizes; (void)n_in; (void)out_size; (void)ws_size;
  const float* x    = (const float*)d_in[0];
  const float* cosb = (const float*)d_in[1];
  const float* sinb = (const float*)d_in[2];
  // d_in[3] = mask (causal, analytic)
  const float* anw  = (const float*)d_in[4];
  const float* fnw  = (const float*)d_in[5];
  const float* wq   = (const float*)d_in[6];
  const float* wk   = (const float*)d_in[7];
  const float* wv   = (const float*)d_in[8];
  const float* wo   = (const float*)d_in[9];
  const float* w1   = (const float*)d_in[10];
  const float* w2   = (const float*)d_in[11];
  const float* w3   = (const float*)d_in[12];

  char* ws = (char*)d_ws;
  const size_t MB = 1048576;
  unsigned short* h     = (unsigned short*)(ws);            // 16 MB: 0..16
  unsigned short* qkvb  = (unsigned short*)(ws + 16*MB);    // 50.3 MB: 16..66.3
  unsigned short* mid   = qkvb;                             // 64 MB (FFN phase): 16..80
  unsigned short* aob   = (unsigned short*)(ws + 67*MB);    // 16 MB: 67..83
  char* wt              = ws + 84*MB;                       // up to 33.6 MB: 84..117.6
  unsigned short* wqkvT = (unsigned short*)wt;              // 25.2 MB
  unsigned short* vtb   = (unsigned short*)wt;              // 16 MB (attn phase)
  unsigned short* woT   = (unsigned short*)wt;              // 8 MB
  unsigned short* wfT   = (unsigned short*)wt;              // 33.6 MB (FFN, sequential)
  float* x1f = (float*)d_out;                               // residual stream in d_out

  dim3 b256(256);
  dim3 tb(32, 8);
  constexpr unsigned LDS256 = (256+256)*32*2*4;  // 131072
  constexpr unsigned LDS128 = (128+256)*32*2*4;  //  98304

  rmsnorm_kernel<<<dim3(MROWS), b256, 0, stream>>>(x, anw, h);

  transpose_w_kernel<<<dim3(64,64), tb, 0, stream>>>(wq, wqkvT,           2048, 2048);
  transpose_w_kernel<<<dim3(64,64), tb, 0, stream>>>(wk, wqkvT + 4194304, 2048, 2048);
  transpose_w_kernel<<<dim3(64,64), tb, 0, stream>>>(wv, wqkvT + 8388608, 2048, 2048);

  gemm_pipe<256,0><<<dim3(384), dim3(512), LDS256, stream>>>(h, wqkvT, nullptr, qkvb, MROWS, 6144, 2048);

  rope_qk<<<dim3(32768), b256, 0, stream>>>(qkvb, cosb, sinb);

  transpose_v_kernel<<<dim3(64,64,2), tb, 0, stream>>>(qkvb + 4096, QKP, vtb);

  attn_kernel<<<dim3(32,32), b256, 0, stream>>>(qkvb, qkvb + 2048, vtb, aob);

  transpose_w_kernel<<<dim3(64,64), tb, 0, stream>>>(wo, woT, 2048, 2048);
  gemm_pipe<128,1><<<dim3(256), dim3(512), LDS128, stream>>>(aob, woT, x, x1f, MROWS, 2048, 2048);

  rmsnorm_kernel<<<dim3(MROWS), b256, 0, stream>>>(x1f, fnw, h);

  // FFN: u = h@w1 -> mid (bf16); then g = h@w3 with fused silu(u)*g in-place.
  transpose_w_kernel<<<dim3(64,256), tb, 0, stream>>>(w1, wfT, 2048, 8192);
  gemm_pipe<256,0><<<dim3(512), dim3(512), LDS256, stream>>>(h, wfT, nullptr, mid, MROWS, 8192, 2048);
  transpose_w_kernel<<<dim3(64,256), tb, 0, stream>>>(w3, wfT, 2048, 8192);
  gemm_pipe<256,3><<<dim3(512), dim3(512), LDS256, stream>>>(h, wfT, nullptr, mid, MROWS, 8192, 2048);

  transpose_w_kernel<<<dim3(256,64), tb, 0, stream>>>(w2, wfT, 8192, 2048);
  gemm_pipe<128,1><<<dim3(256), dim3(512), LDS128, stream>>>(mid, wfT, x1f, (float*)d_out, MROWS, 2048, 8192);
}

// Round 5
// 901.547 us; speedup vs baseline: 1.8502x; 1.1408x over previous
//
#include <hip/hip_runtime.h>

#define DIM 2048
#define HDIM 128
#define NH 16
#define SEQ 2048
#define BATCH 2
#define MROWS (BATCH*SEQ)   // 4096
#define QKP 6144            // qkv row pitch (q|k|v concatenated)

typedef __attribute__((ext_vector_type(8))) short short8;
typedef __attribute__((ext_vector_type(4))) float f32x4;

__device__ __forceinline__ unsigned short f2bf(float f) {
  union { float f; unsigned u; } v; v.f = f;
  unsigned r = v.u + 0x7FFFu + ((v.u >> 16) & 1u);
  return (unsigned short)(r >> 16);
}
__device__ __forceinline__ float bf2f(unsigned short b) {
  union { unsigned u; float f; } v; v.u = ((unsigned)b) << 16;
  return v.f;
}

__device__ __forceinline__ void gload16(const void* g, void* l) {
  __builtin_amdgcn_global_load_lds((const __attribute__((address_space(1))) unsigned int*)g,
                                   (__attribute__((address_space(3))) unsigned int*)l,
                                   16, 0, 0);
}

// ---------------- RMSNorm: fp32 [rows][2048] -> bf16 ----------------
__global__ __launch_bounds__(256) void rmsnorm_kernel(const float* __restrict__ x,
                                                      const float* __restrict__ w,
                                                      unsigned short* __restrict__ out) {
  const int row = blockIdx.x;
  const int t = threadIdx.x;
  const float* xr = x + (size_t)row * DIM;
  float4 v0 = ((const float4*)xr)[t*2];
  float4 v1 = ((const float4*)xr)[t*2+1];
  float ss = v0.x*v0.x + v0.y*v0.y + v0.z*v0.z + v0.w*v0.w
           + v1.x*v1.x + v1.y*v1.y + v1.z*v1.z + v1.w*v1.w;
  #pragma unroll
  for (int i = 1; i < 64; i <<= 1) ss += __shfl_xor(ss, i);
  __shared__ float red[4];
  if ((t & 63) == 0) red[t >> 6] = ss;
  __syncthreads();
  float sum = red[0] + red[1] + red[2] + red[3];
  float sc = rsqrtf(sum * (1.0f/DIM) + 1e-6f);
  const float* wr = w + t*8;
  unsigned short ob[8];
  ob[0] = f2bf(v0.x*sc*wr[0]); ob[1] = f2bf(v0.y*sc*wr[1]);
  ob[2] = f2bf(v0.z*sc*wr[2]); ob[3] = f2bf(v0.w*sc*wr[3]);
  ob[4] = f2bf(v1.x*sc*wr[4]); ob[5] = f2bf(v1.y*sc*wr[5]);
  ob[6] = f2bf(v1.z*sc*wr[6]); ob[7] = f2bf(v1.w*sc*wr[7]);
  uint4 pk;
  pk.x = (unsigned)ob[0] | ((unsigned)ob[1] << 16);
  pk.y = (unsigned)ob[2] | ((unsigned)ob[3] << 16);
  pk.z = (unsigned)ob[4] | ((unsigned)ob[5] << 16);
  pk.w = (unsigned)ob[6] | ((unsigned)ob[7] << 16);
  *((uint4*)(out + (size_t)row*DIM + t*8)) = pk;
}

// ------------- Weight transpose: fp32 [K][N] -> bf16 [N][K] -------------
__global__ __launch_bounds__(256) void transpose_w_kernel(const float* __restrict__ W,
                                                          unsigned short* __restrict__ Wt,
                                                          int K, int N) {
  __shared__ float tile[32][33];
  const int k0 = blockIdx.x*32, n0 = blockIdx.y*32;
  const int tx = threadIdx.x, ty = threadIdx.y;
  #pragma unroll
  for (int i=0;i<4;i++) tile[ty+i*8][tx] = W[(size_t)(k0+ty+i*8)*N + n0+tx];
  __syncthreads();
  #pragma unroll
  for (int i=0;i<4;i++) Wt[(size_t)(n0+ty+i*8)*K + k0+tx] = f2bf(tile[tx][ty+i*8]);
}

// ------------- V transpose (bf16): [b*S][vpitch cols 0..2047] -> [b*2048][S] -------------
__global__ __launch_bounds__(256) void transpose_v_kernel(const unsigned short* __restrict__ v,
                                                          int vpitch,
                                                          unsigned short* __restrict__ vt) {
  __shared__ unsigned short tile[32][33];
  const int b = blockIdx.z;
  const int s0 = blockIdx.x*32, c0 = blockIdx.y*32;
  const int tx = threadIdx.x, ty = threadIdx.y;
  #pragma unroll
  for (int i=0;i<4;i++) tile[ty+i*8][tx] = v[((size_t)(b*SEQ + s0+ty+i*8))*vpitch + c0+tx];
  __syncthreads();
  #pragma unroll
  for (int i=0;i<4;i++) vt[((size_t)(b*DIM + c0+ty+i*8))*SEQ + s0+tx] = tile[tx][ty+i*8];
}

// ------------- RoPE in-place on q|k halves of qkv buffer [4096][QKP] -------------
__global__ __launch_bounds__(256) void rope_qk(unsigned short* __restrict__ qk,
                                               const float* __restrict__ cosb,
                                               const float* __restrict__ sinb) {
  const size_t idx = (size_t)blockIdx.x * 256 + threadIdx.x; // pair index
  const int d = (int)(idx & 63);
  const int h = (int)((idx >> 6) & 31);   // 32 head-slots: q heads 0-15, k heads 16-31
  const int row = (int)(idx >> 11);       // 0..4095
  const int s = row & (SEQ-1);
  const size_t base = (size_t)row * QKP + h*HDIM + d;
  float a  = bf2f(qk[base]);
  float bq = bf2f(qk[base+64]);
  float c1 = cosb[s*HDIM + d],    s1 = sinb[s*HDIM + d];
  float c2 = cosb[s*HDIM + d+64], s2 = sinb[s*HDIM + d+64];
  qk[base]    = f2bf(a*c1 - bq*s1);
  qk[base+64] = f2bf(bq*c2 + a*s2);
}

// ------------- Pipelined GEMM: C[M][N] = A[M][K](bf16) @ Bt[N][K]^T -------------
template<int BM, int EPI>
__global__ __launch_bounds__(512, 2) void gemm_pipe(const unsigned short* __restrict__ A,
                                                    const unsigned short* __restrict__ Bt,
                                                    const float* __restrict__ aux,
                                                    void* __restrict__ outp,
                                                    int M, int N, int K) {
  constexpr int MF = BM / 32;
  constexpr int ASLOT = BM * 32;
  constexpr int SLOT = (BM + 256) * 32;
  extern __shared__ unsigned short ldsd[];
  const int tid = threadIdx.x, l = tid & 63, wid = tid >> 6;
  const int wm = wid >> 2, wn = wid & 3;
  const int lr = l & 15, lg = l >> 4;

  const int nbx = N >> 8;
  const int nwg = gridDim.x;
  const int sb = ((int)blockIdx.x & 7) * (nwg >> 3) + ((int)blockIdx.x >> 3);
  const int bx = sb % nbx, by = sb / nbx;
  const int m0 = by * BM, n0 = bx * 256;

  const int swz  = (((l & 3) ^ ((l >> 3) & 3)) << 3);
  const int rsub = l >> 2;

  const int kx = ((lg ^ ((lr >> 1) & 3)) << 3);
  int aoff[MF];
  #pragma unroll
  for (int mf = 0; mf < MF; mf++) aoff[mf] = (wm*(BM/2) + mf*16 + lr) * 32 + kx;
  int boff[4];
  #pragma unroll
  for (int nf = 0; nf < 4; nf++) boff[nf] = ASLOT + (wn*64 + nf*16 + lr) * 32 + kx;

  f32x4 acc[MF][4] = {};
  const int nt = K >> 5;

  auto STAGE = [&](int tt) {
    unsigned short* sA = ldsd + (tt & 3) * SLOT;
    unsigned short* sB = sA + ASLOT;
    const int k0 = tt << 5;
    #pragma unroll
    for (int c = 0; c < 2; c++) {
      const int rb = (c*8 + wid) * 16;
      gload16(Bt + (size_t)(n0 + rb + rsub) * K + k0 + swz, sB + rb*32);
    }
    if constexpr (BM == 256) {
      #pragma unroll
      for (int c = 0; c < 2; c++) {
        const int rb = (c*8 + wid) * 16;
        gload16(A + (size_t)(m0 + rb + rsub) * K + k0 + swz, sA + rb*32);
      }
    } else {
      const int rb = wid * 16;
      gload16(A + (size_t)(m0 + rb + rsub) * K + k0 + swz, sA + rb*32);
    }
  };

  STAGE(0); STAGE(1); STAGE(2);

  for (int tt = 0; tt < nt; ++tt) {
    if (tt + 3 < nt) {
      STAGE(tt + 3);
      if constexpr (BM == 256) asm volatile("s_waitcnt vmcnt(8)" ::: "memory");
      else                     asm volatile("s_waitcnt vmcnt(6)" ::: "memory");
    } else {
      asm volatile("s_waitcnt vmcnt(0)" ::: "memory");
    }
    __builtin_amdgcn_s_barrier();
    const unsigned short* slot = ldsd + (tt & 3) * SLOT;
    short8 af[MF], bfv[4];
    #pragma unroll
    for (int mf = 0; mf < MF; mf++) af[mf] = *(const short8*)&slot[aoff[mf]];
    #pragma unroll
    for (int nf = 0; nf < 4; nf++) bfv[nf] = *(const short8*)&slot[boff[nf]];
    __builtin_amdgcn_s_setprio(1);
    #pragma unroll
    for (int mf = 0; mf < MF; mf++)
      #pragma unroll
      for (int nf = 0; nf < 4; nf++)
        acc[mf][nf] = __builtin_amdgcn_mfma_f32_16x16x32_bf16(af[mf], bfv[nf], acc[mf][nf], 0, 0, 0);
    __builtin_amdgcn_s_setprio(0);
    __builtin_amdgcn_s_barrier();
  }

  #pragma unroll
  for (int mf = 0; mf < MF; mf++)
    #pragma unroll
    for (int nf = 0; nf < 4; nf++)
      #pragma unroll
      for (int r = 0; r < 4; r++) {
        const int row = m0 + wm*(BM/2) + mf*16 + lg*4 + r;
        const int col = n0 + wn*64 + nf*16 + lr;
        const size_t idx = (size_t)row * N + col;
        if constexpr (EPI == 0) {
          ((unsigned short*)outp)[idx] = f2bf(acc[mf][nf][r]);
        } else if constexpr (EPI == 1) {
          ((float*)outp)[idx] = acc[mf][nf][r] + aux[idx];
        } else {
          float g = acc[mf][nf][r];
          float u = bf2f(((unsigned short*)outp)[idx]);
          float sg = u / (1.0f + __expf(-u));
          ((unsigned short*)outp)[idx] = f2bf(sg * g);
        }
      }
}

// ------------- Flash attention (causal), 128-row q-tiles, KVBLK=64 -------------
// q,k: bf16 [4096][QKP]; vt: bf16 [bh*128][SEQ]
// 4 waves x 32 q-rows. K/V LDS tiles quad-swizzled (^row&7). Row-sum via MFMA
// ones-column; defer-max (THR=8).
__global__ __launch_bounds__(256, 2) void attn_kernel(const unsigned short* __restrict__ q,
                                                      const unsigned short* __restrict__ k,
                                                      const unsigned short* __restrict__ vt,
                                                      unsigned short* __restrict__ ao) {
  const int t = threadIdx.x, lane = t & 63, w = t >> 6;
  const int qt = (int)gridDim.x - 1 - (int)blockIdx.x;   // longest-first
  const int bh = blockIdx.y;
  const int b = bh >> 4, h = bh & 15;
  const int lr = lane & 15, lg = lane >> 4;
  const int q0w = qt*128 + w*32;

  __shared__ __attribute__((aligned(16))) unsigned short Kb[64*128];   // 16 KB
  __shared__ __attribute__((aligned(16))) unsigned short Vb[128*64];   // 16 KB
  __shared__ __attribute__((aligned(16))) unsigned short Ones[16*72];  // row0 = 1.0
  __shared__ __attribute__((aligned(16))) unsigned short P[4][32*72];  // 18 KB
  unsigned short* pw = &P[w][0];

  for (int idx = t; idx < 16*72; idx += 256) Ones[idx] = (idx < 72) ? 0x3F80 : 0;

  // Q fragments: rows q0w + mf*16 + lr
  short8 aq[2][4];
  {
    const unsigned short* qp = q + ((size_t)(b*SEQ + q0w + lr))*QKP + h*HDIM;
    #pragma unroll
    for (int mf=0;mf<2;mf++)
      #pragma unroll
      for (int c=0;c<4;c++) aq[mf][c] = *(const short8*)(qp + (size_t)mf*16*QKP + c*32 + lg*8);
  }

  f32x4 accO[2][8] = {};
  f32x4 accO9[2] = {};
  float mrow[2][4];
  #pragma unroll
  for (int mf=0;mf<2;mf++)
    #pragma unroll
    for (int r=0;r<4;r++) mrow[mf][r] = -3.0e38f;

  const float scale = 0.08838834764831845f; // 1/sqrt(128)
  const unsigned short* kg = k + (size_t)(b*SEQ)*QKP + h*HDIM;
  const unsigned short* vg = vt + (size_t)(bh*HDIM)*SEQ;

  // staging descriptors (dest quad D = i*256 + t; global source pre-swizzled)
  const unsigned short* kga[4]; const unsigned short* vga[4];
  unsigned short* kld[4]; unsigned short* vld[4];
  #pragma unroll
  for (int i=0;i<4;i++) {
    const int D = i*256 + t;
    const int rk = D >> 4, jk = D & 15;
    kga[i] = kg + (size_t)rk*QKP + ((jk ^ (rk & 7)) * 8);
    const int rv = D >> 3, jv = D & 7;
    vga[i] = vg + (size_t)rv*SEQ + ((jv ^ (rv & 7)) * 8);
    kld[i] = &Kb[i*2048 + w*512];
    vld[i] = &Vb[i*2048 + w*512];
  }

  const int KV_END = qt*128 + 128;

  for (int kv0 = 0; kv0 < KV_END; kv0 += 64) {
    #pragma unroll
    for (int i=0;i<4;i++) gload16(kga[i] + (size_t)kv0*QKP, kld[i]);
    #pragma unroll
    for (int i=0;i<4;i++) gload16(vga[i] + kv0, vld[i]);
    __syncthreads();

    if (kv0 < q0w + 32) {
      // ---- QK^T ----
      f32x4 sc[2][4] = {};
      #pragma unroll
      for (int blk=0;blk<4;blk++) {
        const int krow = blk*16 + lr;
        const int sw = (krow & 7) << 3;
        #pragma unroll
        for (int c=0;c<4;c++) {
          short8 bk = *(const short8*)&Kb[krow*128 + ((c*32 + lg*8) ^ sw)];
          sc[0][blk] = __builtin_amdgcn_mfma_f32_16x16x32_bf16(aq[0][c], bk, sc[0][blk], 0,0,0);
          sc[1][blk] = __builtin_amdgcn_mfma_f32_16x16x32_bf16(aq[1][c], bk, sc[1][blk], 0,0,0);
        }
      }
      // ---- scale + (boundary-only) mask ----
      #pragma unroll
      for (int mf=0;mf<2;mf++)
        #pragma unroll
        for (int blk=0;blk<4;blk++)
          #pragma unroll
          for (int r=0;r<4;r++) sc[mf][blk][r] *= scale;
      if (kv0 + 63 > q0w) {
        #pragma unroll
        for (int mf=0;mf<2;mf++)
          #pragma unroll
          for (int blk=0;blk<4;blk++)
            #pragma unroll
            for (int r=0;r<4;r++)
              if (kv0 + blk*16 + lr > q0w + mf*16 + lg*4 + r) sc[mf][blk][r] = -1.0e30f;
      }
      // ---- row max (4 in-reg + 4 shuffles) ----
      float pm[2][4];
      #pragma unroll
      for (int mf=0;mf<2;mf++)
        #pragma unroll
        for (int r=0;r<4;r++) {
          float m0 = fmaxf(fmaxf(sc[mf][0][r], sc[mf][1][r]), fmaxf(sc[mf][2][r], sc[mf][3][r]));
          #pragma unroll
          for (int x=1;x<16;x<<=1) m0 = fmaxf(m0, __shfl_xor(m0, x));
          pm[mf][r] = m0;
        }
      // ---- defer-max: rescale only if max grew past THR=8 ----
      int need = 0;
      #pragma unroll
      for (int mf=0;mf<2;mf++)
        #pragma unroll
        for (int r=0;r<4;r++) need |= (pm[mf][r] > mrow[mf][r] + 8.0f) ? 1 : 0;
      if (__any(need)) {
        #pragma unroll
        for (int mf=0;mf<2;mf++)
          #pragma unroll
          for (int r=0;r<4;r++) {
            const float mn = fmaxf(mrow[mf][r], pm[mf][r]);
            const float fc = __expf(mrow[mf][r] - mn);
            mrow[mf][r] = mn;
            #pragma unroll
            for (int n=0;n<8;n++) accO[mf][n][r] *= fc;
            accO9[mf][r] *= fc;
          }
      }
      // ---- P = exp(s - m) -> LDS ----
      #pragma unroll
      for (int mf=0;mf<2;mf++)
        #pragma unroll
        for (int blk=0;blk<4;blk++)
          #pragma unroll
          for (int r=0;r<4;r++) {
            const float p = __expf(sc[mf][blk][r] - mrow[mf][r]);
            pw[(mf*16 + lg*4 + r)*72 + blk*16 + lr] = f2bf(p);
          }
      // ---- PV (+ ones column for row-sum) ----
      short8 ap[2][2];
      #pragma unroll
      for (int mf=0;mf<2;mf++)
        #pragma unroll
        for (int ks=0;ks<2;ks++) ap[mf][ks] = *(const short8*)&pw[(mf*16 + lr)*72 + ks*32 + lg*8];
      #pragma unroll
      for (int n=0;n<8;n++) {
        #pragma unroll
        for (int ks=0;ks<2;ks++) {
          const int vrow = n*16 + lr;
          const int sw = (vrow & 7) << 3;
          short8 bv = *(const short8*)&Vb[vrow*64 + ((ks*32 + lg*8) ^ sw)];
          accO[0][n] = __builtin_amdgcn_mfma_f32_16x16x32_bf16(ap[0][ks], bv, accO[0][n], 0,0,0);
          accO[1][n] = __builtin_amdgcn_mfma_f32_16x16x32_bf16(ap[1][ks], bv, accO[1][n], 0,0,0);
        }
      }
      #pragma unroll
      for (int ks=0;ks<2;ks++) {
        short8 bv9 = *(const short8*)&Ones[lr*72 + ks*32 + lg*8];
        accO9[0] = __builtin_amdgcn_mfma_f32_16x16x32_bf16(ap[0][ks], bv9, accO9[0], 0,0,0);
        accO9[1] = __builtin_amdgcn_mfma_f32_16x16x32_bf16(ap[1][ks], bv9, accO9[1], 0,0,0);
      }
    }
    __syncthreads();
  }

  // epilogue: broadcast row-sum from lr==0 lanes, normalize, store
  #pragma unroll
  for (int mf=0;mf<2;mf++)
    #pragma unroll
    for (int r=0;r<4;r++) {
      const float lv = __shfl(accO9[mf][r], lane & 48);
      const float inv = 1.0f / lv;
      const size_t row = (size_t)(b*SEQ + q0w + mf*16 + lg*4 + r);
      #pragma unroll
      for (int n=0;n<8;n++)
        ao[row*DIM + h*HDIM + n*16 + lr] = f2bf(accO[mf][n][r] * inv);
    }
}

// ----------------------------------------------------------------------------
extern "C" void kernel_launch(void* const* d_in, const int* in_sizes, int n_in,
                              void* d_out, int out_size, void* d_ws, size_t ws_size,
                              hipStream_t stream) {
  (void)in_sizes; (void)n_in; (void)out_size; (void)ws_size;
  const float* x    = (const float*)d_in[0];
  const float* cosb = (const float*)d_in[1];
  const float* sinb = (const float*)d_in[2];
  // d_in[3] = mask (causal, analytic)
  const float* anw  = (const float*)d_in[4];
  const float* fnw  = (const float*)d_in[5];
  const float* wq   = (const float*)d_in[6];
  const float* wk   = (const float*)d_in[7];
  const float* wv   = (const float*)d_in[8];
  const float* wo   = (const float*)d_in[9];
  const float* w1   = (const float*)d_in[10];
  const float* w2   = (const float*)d_in[11];
  const float* w3   = (const float*)d_in[12];

  char* ws = (char*)d_ws;
  const size_t MB = 1048576;
  unsigned short* h     = (unsigned short*)(ws);            // 16 MB
  unsigned short* qkvb  = (unsigned short*)(ws + 16*MB);    // 50.3 MB
  unsigned short* mid   = qkvb;                             // 64 MB (FFN phase)
  unsigned short* aob   = (unsigned short*)(ws + 67*MB);    // 16 MB
  char* wt              = ws + 84*MB;                       // up to 33.6 MB
  unsigned short* wqkvT = (unsigned short*)wt;
  unsigned short* vtb   = (unsigned short*)wt;
  unsigned short* woT   = (unsigned short*)wt;
  unsigned short* wfT   = (unsigned short*)wt;
  float* x1f = (float*)d_out;

  dim3 b256(256);
  dim3 tb(32, 8);
  constexpr unsigned LDS256 = (256+256)*32*2*4;  // 131072
  constexpr unsigned LDS128 = (128+256)*32*2*4;  //  98304

  rmsnorm_kernel<<<dim3(MROWS), b256, 0, stream>>>(x, anw, h);

  transpose_w_kernel<<<dim3(64,64), tb, 0, stream>>>(wq, wqkvT,           2048, 2048);
  transpose_w_kernel<<<dim3(64,64), tb, 0, stream>>>(wk, wqkvT + 4194304, 2048, 2048);
  transpose_w_kernel<<<dim3(64,64), tb, 0, stream>>>(wv, wqkvT + 8388608, 2048, 2048);

  gemm_pipe<256,0><<<dim3(384), dim3(512), LDS256, stream>>>(h, wqkvT, nullptr, qkvb, MROWS, 6144, 2048);

  rope_qk<<<dim3(32768), b256, 0, stream>>>(qkvb, cosb, sinb);

  transpose_v_kernel<<<dim3(64,64,2), tb, 0, stream>>>(qkvb + 4096, QKP, vtb);

  attn_kernel<<<dim3(16,32), b256, 0, stream>>>(qkvb, qkvb + 2048, vtb, aob);

  transpose_w_kernel<<<dim3(64,64), tb, 0, stream>>>(wo, woT, 2048, 2048);
  gemm_pipe<128,1><<<dim3(256), dim3(512), LDS128, stream>>>(aob, woT, x, x1f, MROWS, 2048, 2048);

  rmsnorm_kernel<<<dim3(MROWS), b256, 0, stream>>>(x1f, fnw, h);

  // FFN: u = h@w1 -> mid (bf16); then g = h@w3 with fused silu(u)*g in-place.
  transpose_w_kernel<<<dim3(64,256), tb, 0, stream>>>(w1, wfT, 2048, 8192);
  gemm_pipe<256,0><<<dim3(512), dim3(512), LDS256, stream>>>(h, wfT, nullptr, mid, MROWS, 8192, 2048);
  transpose_w_kernel<<<dim3(64,256), tb, 0, stream>>>(w3, wfT, 2048, 8192);
  gemm_pipe<256,3><<<dim3(512), dim3(512), LDS256, stream>>>(h, wfT, nullptr, mid, MROWS, 8192, 2048);

  transpose_w_kernel<<<dim3(256,64), tb, 0, stream>>>(w2, wfT, 8192, 2048);
  gemm_pipe<128,1><<<dim3(256), dim3(512), LDS128, stream>>>(mid, wfT, x1f, (float*)d_out, MROWS, 2048, 8192);
}